// Round 1
// baseline (987.276 us; speedup 1.0000x reference)
//
#include <hip/hip_runtime.h>
#include <cstdint>
#include <cstddef>

static inline size_t align_up(size_t v, size_t a) { return (v + a - 1) & ~(a - 1); }

// ---------------- edge-index dtype detect (int64 vs int32) ----------------
__global__ void detect_kernel(const unsigned int* e, int n_check, int* flag) {
  __shared__ int bad;
  if (threadIdx.x == 0) bad = 0;
  __syncthreads();
  for (int i = threadIdx.x; i < n_check; i += blockDim.x)
    if (e[2 * i + 1] != 0u) bad = 1;  // benign race, same value
  __syncthreads();
  if (threadIdx.x == 0) *flag = bad ? 0 : 1;  // 1 => int64 layout
}

__device__ inline int load_edge(const void* eidx, int is64, size_t idx) {
  if (is64) return (int)((const long long*)eidx)[idx];
  return ((const int*)eidx)[idx];
}

// ---------------- CSR build ----------------
__global__ void hist_kernel(const void* eidx, const int* flag, int E, int* cnt) {
  int e = blockIdx.x * blockDim.x + threadIdx.x;
  if (e >= E) return;
  int d = load_edge(eidx, *flag, (size_t)E + e);
  atomicAdd(&cnt[d], 1);
}

__global__ void scan1_kernel(const int* cnt, int* bsum, int N) {
  __shared__ int sd[256];
  int b = blockIdx.x, t = threadIdx.x;
  int base = b * 1024;
  int s = 0;
  for (int i = t; i < 1024; i += 256) { int idx = base + i; if (idx < N) s += cnt[idx]; }
  sd[t] = s; __syncthreads();
  for (int off = 128; off > 0; off >>= 1) { if (t < off) sd[t] += sd[t + off]; __syncthreads(); }
  if (t == 0) bsum[b] = sd[0];
}

__global__ void scan2_kernel(int* bsum, int nb, int* rowptr, int N) {
  if (blockIdx.x == 0 && threadIdx.x == 0) {
    int run = 0;
    for (int i = 0; i < nb; ++i) { int v = bsum[i]; bsum[i] = run; run += v; }
    rowptr[N] = run;
  }
}

__global__ void scan3_kernel(const int* cnt, const int* bsum, int* rowptr, int N) {
  __shared__ int sd[256];
  int b = blockIdx.x, t = threadIdx.x;
  int base = b * 1024 + t * 4;
  int v[4]; int s = 0;
#pragma unroll
  for (int j = 0; j < 4; ++j) { int idx = base + j; v[j] = (idx < N) ? cnt[idx] : 0; s += v[j]; }
  sd[t] = s; __syncthreads();
  for (int off = 1; off < 256; off <<= 1) {
    int u = (t >= off) ? sd[t - off] : 0;
    __syncthreads();
    sd[t] += u;
    __syncthreads();
  }
  int run = bsum[b] + (sd[t] - s);  // exclusive prefix
#pragma unroll
  for (int j = 0; j < 4; ++j) {
    int idx = base + j;
    if (idx < N) rowptr[idx] = run;
    run += v[j];
  }
}

__global__ void scatter_kernel(const void* eidx, const int* flag, int E,
                               const int* rowptr, int* fill, int* csr_src) {
  int e = blockIdx.x * blockDim.x + threadIdx.x;
  if (e >= E) return;
  int is64 = *flag;
  int s = load_edge(eidx, is64, (size_t)e);
  int d = load_edge(eidx, is64, (size_t)E + e);
  int pos = rowptr[d] + atomicAdd(&fill[d], 1);
  csr_src[pos] = s;
}

// ---------------- GEMM1: h1 = x @ W1 [N,128]x[128,128], + al1_s/al1_d ----------------
__global__ __launch_bounds__(256) void gemm1_kernel(
    const float* __restrict__ x, const float* __restrict__ W1,
    const float* __restrict__ a1s, const float* __restrict__ a1d,
    float* __restrict__ h1, float* __restrict__ al_s, float* __restrict__ al_d, int N) {
  __shared__ float sW[128 * 64];   // half of W1: [k][c], 32 KB
  __shared__ float sx[32 * 129];   // 32 rows of x, padded stride
  const int t = threadIdx.x;
  const int row0 = blockIdx.x * 32;
  // stage x tile (scalar stores due to padded stride)
  for (int i = t; i < 32 * 32; i += 256) {
    int r = i >> 5, c4 = (i & 31) * 4;
    float4 v = make_float4(0.f, 0.f, 0.f, 0.f);
    if (row0 + r < N) v = *(const float4*)(x + (size_t)(row0 + r) * 128 + c4);
    float* dst = sx + r * 129 + c4;
    dst[0] = v.x; dst[1] = v.y; dst[2] = v.z; dst[3] = v.w;
  }
  const int tx = t & 15, ty = t >> 4;  // tx: 16 col-groups of 4; ty: 16 row-groups of 2
  const int r0 = 2 * ty, r1 = 2 * ty + 1;
  for (int half = 0; half < 2; ++half) {
    __syncthreads();
    for (int i = t; i < 128 * 16; i += 256) {
      int k = i >> 4, c4 = (i & 15) * 4;
      *(float4*)(sW + k * 64 + c4) = *(const float4*)(W1 + (size_t)k * 128 + half * 64 + c4);
    }
    __syncthreads();
    float acc0[4] = {0.f, 0.f, 0.f, 0.f}, acc1[4] = {0.f, 0.f, 0.f, 0.f};
#pragma unroll 4
    for (int k = 0; k < 128; ++k) {
      float4 w = *(const float4*)(sW + k * 64 + tx * 4);
      float xa = sx[r0 * 129 + k];
      float xb = sx[r1 * 129 + k];
      acc0[0] += xa * w.x; acc0[1] += xa * w.y; acc0[2] += xa * w.z; acc0[3] += xa * w.w;
      acc1[0] += xb * w.x; acc1[1] += xb * w.y; acc1[2] += xb * w.z; acc1[3] += xb * w.w;
    }
    int col = half * 64 + tx * 4;
    int head = col >> 5;
    float as0 = a1s[col], as1 = a1s[col + 1], as2 = a1s[col + 2], as3 = a1s[col + 3];
    float ad0 = a1d[col], ad1 = a1d[col + 1], ad2 = a1d[col + 2], ad3 = a1d[col + 3];
    int g0 = row0 + r0, g1 = row0 + r1;
    if (g0 < N) *(float4*)(h1 + (size_t)g0 * 128 + col) = make_float4(acc0[0], acc0[1], acc0[2], acc0[3]);
    if (g1 < N) *(float4*)(h1 + (size_t)g1 * 128 + col) = make_float4(acc1[0], acc1[1], acc1[2], acc1[3]);
    float ps0 = acc0[0] * as0 + acc0[1] * as1 + acc0[2] * as2 + acc0[3] * as3;
    float pd0 = acc0[0] * ad0 + acc0[1] * ad1 + acc0[2] * ad2 + acc0[3] * ad3;
    float ps1 = acc1[0] * as0 + acc1[1] * as1 + acc1[2] * as2 + acc1[3] * as3;
    float pd1 = acc1[0] * ad0 + acc1[1] * ad1 + acc1[2] * ad2 + acc1[3] * ad3;
#pragma unroll
    for (int off = 1; off < 8; off <<= 1) {
      ps0 += __shfl_xor(ps0, off); pd0 += __shfl_xor(pd0, off);
      ps1 += __shfl_xor(ps1, off); pd1 += __shfl_xor(pd1, off);
    }
    if ((tx & 7) == 0) {
      if (g0 < N) { al_s[(size_t)g0 * 4 + head] = ps0; al_d[(size_t)g0 * 4 + head] = pd0; }
      if (g1 < N) { al_s[(size_t)g1 * 4 + head] = ps1; al_d[(size_t)g1 * 4 + head] = pd1; }
    }
  }
}

// ---------------- Layer-1 aggregate: one wave per dst node ----------------
__global__ __launch_bounds__(256) void agg1_kernel(
    const int* __restrict__ rowptr, const int* __restrict__ csr_src,
    const float* __restrict__ h1, const float* __restrict__ al_s, const float* __restrict__ al_d,
    const float* __restrict__ b1, float* __restrict__ hout, int N) {
  int gid = blockIdx.x * blockDim.x + threadIdx.x;
  int d = gid >> 6;
  if (d >= N) return;
  int lane = threadIdx.x & 63;
  int head = lane >> 4;  // features 2*lane, 2*lane+1 are in head (2*lane)/32
  float ald = al_d[(size_t)d * 4 + head];
  float accx = 0.f, accy = 0.f, den = 0.f;
  {  // self loop
    float e = al_s[(size_t)d * 4 + head] + ald;
    e = e > 0.f ? e : 0.2f * e;
    float ex = __expf(e);
    float2 hv = *(const float2*)(h1 + (size_t)d * 128 + 2 * lane);
    accx += ex * hv.x; accy += ex * hv.y; den += ex;
  }
  int beg = rowptr[d], end = rowptr[d + 1];
  int i = beg;
  for (; i + 2 <= end; i += 2) {
    int s0 = csr_src[i], s1 = csr_src[i + 1];
    float e0 = al_s[(size_t)s0 * 4 + head] + ald;
    float e1 = al_s[(size_t)s1 * 4 + head] + ald;
    float2 h0 = *(const float2*)(h1 + (size_t)s0 * 128 + 2 * lane);
    float2 h1v = *(const float2*)(h1 + (size_t)s1 * 128 + 2 * lane);
    e0 = e0 > 0.f ? e0 : 0.2f * e0;
    e1 = e1 > 0.f ? e1 : 0.2f * e1;
    float ex0 = __expf(e0), ex1 = __expf(e1);
    accx += ex0 * h0.x + ex1 * h1v.x;
    accy += ex0 * h0.y + ex1 * h1v.y;
    den += ex0 + ex1;
  }
  if (i < end) {
    int s0 = csr_src[i];
    float e0 = al_s[(size_t)s0 * 4 + head] + ald;
    float2 h0 = *(const float2*)(h1 + (size_t)s0 * 128 + 2 * lane);
    e0 = e0 > 0.f ? e0 : 0.2f * e0;
    float ex0 = __expf(e0);
    accx += ex0 * h0.x; accy += ex0 * h0.y; den += ex0;
  }
  float inv = 1.f / den;
  float ox = accx * inv + b1[2 * lane];
  float oy = accy * inv + b1[2 * lane + 1];
  ox = ox > 0.f ? ox : expm1f(ox);  // ELU
  oy = oy > 0.f ? oy : expm1f(oy);
  *(float2*)(hout + (size_t)d * 128 + 2 * lane) = make_float2(ox, oy);
}

// ---------------- GEMM2: h2 = h_elu @ W2 [N,128]x[128,32], + al2 ----------------
__global__ __launch_bounds__(256) void gemm2_kernel(
    const float* __restrict__ hin, const float* __restrict__ W2,
    const float* __restrict__ a2s, const float* __restrict__ a2d,
    float* __restrict__ h2, float* __restrict__ al_s, float* __restrict__ al_d, int N) {
  __shared__ float sW[128 * 32];
  __shared__ float sx[32 * 129];
  const int t = threadIdx.x;
  const int row0 = blockIdx.x * 32;
  for (int i = t; i < 128 * 8; i += 256) {
    int k = i >> 3, c4 = (i & 7) * 4;
    *(float4*)(sW + k * 32 + c4) = *(const float4*)(W2 + (size_t)k * 32 + c4);
  }
  for (int i = t; i < 32 * 32; i += 256) {
    int r = i >> 5, c4 = (i & 31) * 4;
    float4 v = make_float4(0.f, 0.f, 0.f, 0.f);
    if (row0 + r < N) v = *(const float4*)(hin + (size_t)(row0 + r) * 128 + c4);
    float* dst = sx + r * 129 + c4;
    dst[0] = v.x; dst[1] = v.y; dst[2] = v.z; dst[3] = v.w;
  }
  __syncthreads();
  const int tx = t & 7, ty = t >> 3;  // tx: 8 col-groups of 4; ty: 32 rows
  float acc[4] = {0.f, 0.f, 0.f, 0.f};
#pragma unroll 4
  for (int k = 0; k < 128; ++k) {
    float4 w = *(const float4*)(sW + k * 32 + tx * 4);
    float xv = sx[ty * 129 + k];
    acc[0] += xv * w.x; acc[1] += xv * w.y; acc[2] += xv * w.z; acc[3] += xv * w.w;
  }
  int row = row0 + ty;
  int col = tx * 4;
  float ps = acc[0] * a2s[col] + acc[1] * a2s[col + 1] + acc[2] * a2s[col + 2] + acc[3] * a2s[col + 3];
  float pd = acc[0] * a2d[col] + acc[1] * a2d[col + 1] + acc[2] * a2d[col + 2] + acc[3] * a2d[col + 3];
#pragma unroll
  for (int off = 1; off < 8; off <<= 1) { ps += __shfl_xor(ps, off); pd += __shfl_xor(pd, off); }
  if (row < N) {
    *(float4*)(h2 + (size_t)row * 32 + col) = make_float4(acc[0], acc[1], acc[2], acc[3]);
    if (tx == 0) { al_s[row] = ps; al_d[row] = pd; }
  }
}

// ---------------- Layer-2 aggregate + pooled partials: half-wave per node ----------------
__global__ __launch_bounds__(256) void agg2_kernel(
    const int* __restrict__ rowptr, const int* __restrict__ csr_src,
    const float* __restrict__ h2, const float* __restrict__ al_s, const float* __restrict__ al_d,
    float* __restrict__ partial, int N) {
  __shared__ float sp[8 * 32];
  int t = threadIdx.x;
  int slot = t >> 5;   // 8 nodes per block
  int c = t & 31;
  int node = blockIdx.x * 8 + slot;
  float o = 0.f;
  if (node < N) {
    float ald = al_d[node];
    float acc = 0.f, den = 0.f;
    {  // self loop
      float e = al_s[node] + ald;
      e = e > 0.f ? e : 0.2f * e;
      float ex = __expf(e);
      acc += ex * h2[(size_t)node * 32 + c]; den += ex;
    }
    int beg = rowptr[node], end = rowptr[node + 1];
    for (int i = beg; i < end; ++i) {
      int s = csr_src[i];
      float e = al_s[s] + ald;
      e = e > 0.f ? e : 0.2f * e;
      float ex = __expf(e);
      acc += ex * h2[(size_t)s * 32 + c];
      den += ex;
    }
    o = acc / den;
  }
  sp[slot * 32 + c] = o;
  __syncthreads();
  if (t < 32) {
    float s = 0.f;
#pragma unroll
    for (int j = 0; j < 8; ++j) s += sp[j * 32 + t];
    partial[(size_t)blockIdx.x * 32 + t] = s;
  }
}

// ---------------- final: pool mean + linear + softmax ----------------
__global__ void final_kernel(const float* __restrict__ partial, int nb,
                             const float* __restrict__ b2, const float* __restrict__ linW,
                             const float* __restrict__ linb, float* __restrict__ out, int N) {
  __shared__ float sd[256];
  __shared__ float pooled[32];
  int t = threadIdx.x;
  int c = t & 31, g = t >> 5;
  float s = 0.f;
  for (int i = g; i < nb; i += 8) s += partial[(size_t)i * 32 + c];
  sd[t] = s; __syncthreads();
  if (t < 32) {
    float tot = 0.f;
#pragma unroll
    for (int j = 0; j < 8; ++j) tot += sd[j * 32 + t];
    pooled[t] = tot / (float)N + b2[t];
  }
  __syncthreads();
  if (t == 0) {
    float lg[3];
    for (int j = 0; j < 3; ++j) lg[j] = linb[j];
    for (int cc = 0; cc < 32; ++cc)
      for (int j = 0; j < 3; ++j) lg[j] += pooled[cc] * linW[cc * 3 + j];
    float m = fmaxf(lg[0], fmaxf(lg[1], lg[2]));
    float e0 = __expf(lg[0] - m), e1 = __expf(lg[1] - m), e2 = __expf(lg[2] - m);
    float inv = 1.f / (e0 + e1 + e2);
    out[0] = e0 * inv; out[1] = e1 * inv; out[2] = e2 * inv;
  }
}

extern "C" void kernel_launch(void* const* d_in, const int* in_sizes, int n_in,
                              void* d_out, int out_size, void* d_ws, size_t ws_size,
                              hipStream_t stream) {
  const float* x    = (const float*)d_in[0];
  const void*  eidx = d_in[1];
  const float* W1   = (const float*)d_in[2];
  const float* a1s  = (const float*)d_in[3];
  const float* a1d  = (const float*)d_in[4];
  const float* b1   = (const float*)d_in[5];
  const float* W2   = (const float*)d_in[6];
  const float* a2s  = (const float*)d_in[7];
  const float* a2d  = (const float*)d_in[8];
  const float* b2   = (const float*)d_in[9];
  const float* linW = (const float*)d_in[10];
  const float* linb = (const float*)d_in[11];
  float* out = (float*)d_out;

  const int N = in_sizes[0] / 128;
  const int E = in_sizes[1] / 2;

  char* ws = (char*)d_ws;
  size_t off = 0;
  auto alloc = [&](size_t bytes) -> void* {
    size_t o = off;
    off = align_up(off + bytes, 256);
    return (void*)(ws + o);
  };
  int* cnt    = (int*)alloc((size_t)2 * N * sizeof(int));  // cnt + fill contiguous for one memset
  int* fill   = cnt + N;
  int* flag   = (int*)alloc(sizeof(int));
  int* rowptr = (int*)alloc((size_t)(N + 1) * sizeof(int));
  const int nb1024 = (N + 1023) / 1024;
  int* bsum   = (int*)alloc((size_t)nb1024 * sizeof(int));
  int* csr    = (int*)alloc((size_t)E * sizeof(int));
  float* al1s = (float*)alloc((size_t)N * 4 * sizeof(float));
  float* al1d = (float*)alloc((size_t)N * 4 * sizeof(float));
  float* al2s = (float*)alloc((size_t)N * sizeof(float));
  float* al2d = (float*)alloc((size_t)N * sizeof(float));
  float* h1   = (float*)alloc((size_t)N * 128 * sizeof(float));  // reused as h2 after agg1
  float* hout = (float*)alloc((size_t)N * 128 * sizeof(float));
  const int nAggBlocks = (N + 7) / 8;
  float* partial = (float*)alloc((size_t)nAggBlocks * 32 * sizeof(float));
  float* h2 = h1;  // alias: h1 dead after agg1_kernel

  hipMemsetAsync(cnt, 0, (size_t)2 * N * sizeof(int), stream);
  int ncheck = E < 512 ? E : 512;
  detect_kernel<<<1, 256, 0, stream>>>((const unsigned int*)eidx, ncheck, flag);
  hist_kernel<<<(E + 255) / 256, 256, 0, stream>>>(eidx, flag, E, cnt);
  scan1_kernel<<<nb1024, 256, 0, stream>>>(cnt, bsum, N);
  scan2_kernel<<<1, 1, 0, stream>>>(bsum, nb1024, rowptr, N);
  scan3_kernel<<<nb1024, 256, 0, stream>>>(cnt, bsum, rowptr, N);
  scatter_kernel<<<(E + 255) / 256, 256, 0, stream>>>(eidx, flag, E, rowptr, fill, csr);
  gemm1_kernel<<<(N + 31) / 32, 256, 0, stream>>>(x, W1, a1s, a1d, h1, al1s, al1d, N);
  agg1_kernel<<<(N * 64 + 255) / 256, 256, 0, stream>>>(rowptr, csr, h1, al1s, al1d, b1, hout, N);
  gemm2_kernel<<<(N + 31) / 32, 256, 0, stream>>>(hout, W2, a2s, a2d, h2, al2s, al2d, N);
  agg2_kernel<<<nAggBlocks, 256, 0, stream>>>(rowptr, csr, h2, al2s, al2d, partial, N);
  final_kernel<<<1, 256, 0, stream>>>(partial, nAggBlocks, b2, linW, linb, out, N);
}

// Round 2
// 611.402 us; speedup vs baseline: 1.6148x; 1.6148x over previous
//
#include <hip/hip_runtime.h>
#include <cstdint>
#include <cstddef>

static inline size_t align_up(size_t v, size_t a) { return (v + a - 1) & ~(a - 1); }

// ---------------- edge-index dtype detect (int64 vs int32) ----------------
__global__ void detect_kernel(const unsigned int* e, int n_check, int* flag) {
  __shared__ int bad;
  if (threadIdx.x == 0) bad = 0;
  __syncthreads();
  for (int i = threadIdx.x; i < n_check; i += blockDim.x)
    if (e[2 * i + 1] != 0u) bad = 1;  // benign race, same value
  __syncthreads();
  if (threadIdx.x == 0) *flag = bad ? 0 : 1;  // 1 => int64 layout
}

__device__ inline int load_edge(const void* eidx, int is64, size_t idx) {
  if (is64) return (int)((const long long*)eidx)[idx];
  return ((const int*)eidx)[idx];
}

// ---------------- CSR build ----------------
__global__ void hist_kernel(const void* eidx, const int* flag, int E, int* cnt) {
  int e = blockIdx.x * blockDim.x + threadIdx.x;
  if (e >= E) return;
  int d = load_edge(eidx, *flag, (size_t)E + e);
  atomicAdd(&cnt[d], 1);
}

__global__ void scan1_kernel(const int* cnt, int* bsum, int N) {
  __shared__ int sd[256];
  int b = blockIdx.x, t = threadIdx.x;
  int base = b * 1024;
  int s = 0;
  for (int i = t; i < 1024; i += 256) { int idx = base + i; if (idx < N) s += cnt[idx]; }
  sd[t] = s; __syncthreads();
  for (int off = 128; off > 0; off >>= 1) { if (t < off) sd[t] += sd[t + off]; __syncthreads(); }
  if (t == 0) bsum[b] = sd[0];
}

__global__ void scan2_kernel(int* bsum, int nb, int* rowptr, int N) {
  if (blockIdx.x == 0 && threadIdx.x == 0) {
    int run = 0;
    for (int i = 0; i < nb; ++i) { int v = bsum[i]; bsum[i] = run; run += v; }
    rowptr[N] = run;
  }
}

__global__ void scan3_kernel(const int* cnt, const int* bsum, int* rowptr, int N) {
  __shared__ int sd[256];
  int b = blockIdx.x, t = threadIdx.x;
  int base = b * 1024 + t * 4;
  int v[4]; int s = 0;
#pragma unroll
  for (int j = 0; j < 4; ++j) { int idx = base + j; v[j] = (idx < N) ? cnt[idx] : 0; s += v[j]; }
  sd[t] = s; __syncthreads();
  for (int off = 1; off < 256; off <<= 1) {
    int u = (t >= off) ? sd[t - off] : 0;
    __syncthreads();
    sd[t] += u;
    __syncthreads();
  }
  int run = bsum[b] + (sd[t] - s);  // exclusive prefix
#pragma unroll
  for (int j = 0; j < 4; ++j) {
    int idx = base + j;
    if (idx < N) rowptr[idx] = run;
    run += v[j];
  }
}

__global__ void scatter_kernel(const void* eidx, const int* flag, int E,
                               const int* rowptr, int* fill, int* csr_src) {
  int e = blockIdx.x * blockDim.x + threadIdx.x;
  if (e >= E) return;
  int is64 = *flag;
  int s = load_edge(eidx, is64, (size_t)e);
  int d = load_edge(eidx, is64, (size_t)E + e);
  int pos = rowptr[d] + atomicAdd(&fill[d], 1);
  csr_src[pos] = s;
}

// ---------------- GEMM1: h1 = x @ W1 [N,128]x[128,128], + al1_s/al1_d ----------------
__global__ __launch_bounds__(256) void gemm1_kernel(
    const float* __restrict__ x, const float* __restrict__ W1,
    const float* __restrict__ a1s, const float* __restrict__ a1d,
    float* __restrict__ h1, float* __restrict__ al_s, float* __restrict__ al_d, int N) {
  __shared__ float sW[128 * 64];   // half of W1: [k][c], 32 KB
  __shared__ float sx[32 * 129];   // 32 rows of x, padded stride
  const int t = threadIdx.x;
  const int row0 = blockIdx.x * 32;
  // stage x tile (scalar stores due to padded stride)
  for (int i = t; i < 32 * 32; i += 256) {
    int r = i >> 5, c4 = (i & 31) * 4;
    float4 v = make_float4(0.f, 0.f, 0.f, 0.f);
    if (row0 + r < N) v = *(const float4*)(x + (size_t)(row0 + r) * 128 + c4);
    float* dst = sx + r * 129 + c4;
    dst[0] = v.x; dst[1] = v.y; dst[2] = v.z; dst[3] = v.w;
  }
  const int tx = t & 15, ty = t >> 4;  // tx: 16 col-groups of 4; ty: 16 row-groups of 2
  const int r0 = 2 * ty, r1 = 2 * ty + 1;
  for (int half = 0; half < 2; ++half) {
    __syncthreads();
    for (int i = t; i < 128 * 16; i += 256) {
      int k = i >> 4, c4 = (i & 15) * 4;
      *(float4*)(sW + k * 64 + c4) = *(const float4*)(W1 + (size_t)k * 128 + half * 64 + c4);
    }
    __syncthreads();
    float acc0[4] = {0.f, 0.f, 0.f, 0.f}, acc1[4] = {0.f, 0.f, 0.f, 0.f};
#pragma unroll 4
    for (int k = 0; k < 128; ++k) {
      float4 w = *(const float4*)(sW + k * 64 + tx * 4);
      float xa = sx[r0 * 129 + k];
      float xb = sx[r1 * 129 + k];
      acc0[0] += xa * w.x; acc0[1] += xa * w.y; acc0[2] += xa * w.z; acc0[3] += xa * w.w;
      acc1[0] += xb * w.x; acc1[1] += xb * w.y; acc1[2] += xb * w.z; acc1[3] += xb * w.w;
    }
    int col = half * 64 + tx * 4;
    int head = col >> 5;
    float as0 = a1s[col], as1 = a1s[col + 1], as2 = a1s[col + 2], as3 = a1s[col + 3];
    float ad0 = a1d[col], ad1 = a1d[col + 1], ad2 = a1d[col + 2], ad3 = a1d[col + 3];
    int g0 = row0 + r0, g1 = row0 + r1;
    if (g0 < N) *(float4*)(h1 + (size_t)g0 * 128 + col) = make_float4(acc0[0], acc0[1], acc0[2], acc0[3]);
    if (g1 < N) *(float4*)(h1 + (size_t)g1 * 128 + col) = make_float4(acc1[0], acc1[1], acc1[2], acc1[3]);
    float ps0 = acc0[0] * as0 + acc0[1] * as1 + acc0[2] * as2 + acc0[3] * as3;
    float pd0 = acc0[0] * ad0 + acc0[1] * ad1 + acc0[2] * ad2 + acc0[3] * ad3;
    float ps1 = acc1[0] * as0 + acc1[1] * as1 + acc1[2] * as2 + acc1[3] * as3;
    float pd1 = acc1[0] * ad0 + acc1[1] * ad1 + acc1[2] * ad2 + acc1[3] * ad3;
#pragma unroll
    for (int off = 1; off < 8; off <<= 1) {
      ps0 += __shfl_xor(ps0, off); pd0 += __shfl_xor(pd0, off);
      ps1 += __shfl_xor(ps1, off); pd1 += __shfl_xor(pd1, off);
    }
    if ((tx & 7) == 0) {
      if (g0 < N) { al_s[(size_t)g0 * 4 + head] = ps0; al_d[(size_t)g0 * 4 + head] = pd0; }
      if (g1 < N) { al_s[(size_t)g1 * 4 + head] = ps1; al_d[(size_t)g1 * 4 + head] = pd1; }
    }
  }
}

// ---------------- Layer-1 aggregate: one wave per dst node ----------------
__global__ __launch_bounds__(256) void agg1_kernel(
    const int* __restrict__ rowptr, const int* __restrict__ csr_src,
    const float* __restrict__ h1, const float* __restrict__ al_s, const float* __restrict__ al_d,
    const float* __restrict__ b1, float* __restrict__ hout, int N) {
  int gid = blockIdx.x * blockDim.x + threadIdx.x;
  int d = gid >> 6;
  if (d >= N) return;
  int lane = threadIdx.x & 63;
  int head = lane >> 4;  // features 2*lane, 2*lane+1 are in head (2*lane)/32
  float ald = al_d[(size_t)d * 4 + head];
  float accx = 0.f, accy = 0.f, den = 0.f;
  {  // self loop
    float e = al_s[(size_t)d * 4 + head] + ald;
    e = e > 0.f ? e : 0.2f * e;
    float ex = __expf(e);
    float2 hv = *(const float2*)(h1 + (size_t)d * 128 + 2 * lane);
    accx += ex * hv.x; accy += ex * hv.y; den += ex;
  }
  int beg = rowptr[d], end = rowptr[d + 1];
  int i = beg;
  for (; i + 2 <= end; i += 2) {
    int s0 = csr_src[i], s1 = csr_src[i + 1];
    float e0 = al_s[(size_t)s0 * 4 + head] + ald;
    float e1 = al_s[(size_t)s1 * 4 + head] + ald;
    float2 h0 = *(const float2*)(h1 + (size_t)s0 * 128 + 2 * lane);
    float2 h1v = *(const float2*)(h1 + (size_t)s1 * 128 + 2 * lane);
    e0 = e0 > 0.f ? e0 : 0.2f * e0;
    e1 = e1 > 0.f ? e1 : 0.2f * e1;
    float ex0 = __expf(e0), ex1 = __expf(e1);
    accx += ex0 * h0.x + ex1 * h1v.x;
    accy += ex0 * h0.y + ex1 * h1v.y;
    den += ex0 + ex1;
  }
  if (i < end) {
    int s0 = csr_src[i];
    float e0 = al_s[(size_t)s0 * 4 + head] + ald;
    float2 h0 = *(const float2*)(h1 + (size_t)s0 * 128 + 2 * lane);
    e0 = e0 > 0.f ? e0 : 0.2f * e0;
    float ex0 = __expf(e0);
    accx += ex0 * h0.x; accy += ex0 * h0.y; den += ex0;
  }
  float inv = 1.f / den;
  float ox = accx * inv + b1[2 * lane];
  float oy = accy * inv + b1[2 * lane + 1];
  ox = ox > 0.f ? ox : expm1f(ox);  // ELU
  oy = oy > 0.f ? oy : expm1f(oy);
  *(float2*)(hout + (size_t)d * 128 + 2 * lane) = make_float2(ox, oy);
}

// ---------------- GEMM2: h2 = h_elu @ W2 [N,128]x[128,32], + al2 ----------------
__global__ __launch_bounds__(256) void gemm2_kernel(
    const float* __restrict__ hin, const float* __restrict__ W2,
    const float* __restrict__ a2s, const float* __restrict__ a2d,
    float* __restrict__ h2, float* __restrict__ al_s, float* __restrict__ al_d, int N) {
  __shared__ float sW[128 * 32];
  __shared__ float sx[32 * 129];
  const int t = threadIdx.x;
  const int row0 = blockIdx.x * 32;
  for (int i = t; i < 128 * 8; i += 256) {
    int k = i >> 3, c4 = (i & 7) * 4;
    *(float4*)(sW + k * 32 + c4) = *(const float4*)(W2 + (size_t)k * 32 + c4);
  }
  for (int i = t; i < 32 * 32; i += 256) {
    int r = i >> 5, c4 = (i & 31) * 4;
    float4 v = make_float4(0.f, 0.f, 0.f, 0.f);
    if (row0 + r < N) v = *(const float4*)(hin + (size_t)(row0 + r) * 128 + c4);
    float* dst = sx + r * 129 + c4;
    dst[0] = v.x; dst[1] = v.y; dst[2] = v.z; dst[3] = v.w;
  }
  __syncthreads();
  const int tx = t & 7, ty = t >> 3;  // tx: 8 col-groups of 4; ty: 32 rows
  float acc[4] = {0.f, 0.f, 0.f, 0.f};
#pragma unroll 4
  for (int k = 0; k < 128; ++k) {
    float4 w = *(const float4*)(sW + k * 32 + tx * 4);
    float xv = sx[ty * 129 + k];
    acc[0] += xv * w.x; acc[1] += xv * w.y; acc[2] += xv * w.z; acc[3] += xv * w.w;
  }
  int row = row0 + ty;
  int col = tx * 4;
  float ps = acc[0] * a2s[col] + acc[1] * a2s[col + 1] + acc[2] * a2s[col + 2] + acc[3] * a2s[col + 3];
  float pd = acc[0] * a2d[col] + acc[1] * a2d[col + 1] + acc[2] * a2d[col + 2] + acc[3] * a2d[col + 3];
#pragma unroll
  for (int off = 1; off < 8; off <<= 1) { ps += __shfl_xor(ps, off); pd += __shfl_xor(pd, off); }
  if (row < N) {
    *(float4*)(h2 + (size_t)row * 32 + col) = make_float4(acc[0], acc[1], acc[2], acc[3]);
    if (tx == 0) { al_s[row] = ps; al_d[row] = pd; }
  }
}

// ---------------- Layer-2 aggregate + pooled partials: half-wave per node ----------------
__global__ __launch_bounds__(256) void agg2_kernel(
    const int* __restrict__ rowptr, const int* __restrict__ csr_src,
    const float* __restrict__ h2, const float* __restrict__ al_s, const float* __restrict__ al_d,
    float* __restrict__ partial, int N) {
  __shared__ float sp[8 * 32];
  int t = threadIdx.x;
  int slot = t >> 5;   // 8 nodes per block
  int c = t & 31;
  int node = blockIdx.x * 8 + slot;
  float o = 0.f;
  if (node < N) {
    float ald = al_d[node];
    float acc = 0.f, den = 0.f;
    {  // self loop
      float e = al_s[node] + ald;
      e = e > 0.f ? e : 0.2f * e;
      float ex = __expf(e);
      acc += ex * h2[(size_t)node * 32 + c]; den += ex;
    }
    int beg = rowptr[node], end = rowptr[node + 1];
    for (int i = beg; i < end; ++i) {
      int s = csr_src[i];
      float e = al_s[s] + ald;
      e = e > 0.f ? e : 0.2f * e;
      float ex = __expf(e);
      acc += ex * h2[(size_t)s * 32 + c];
      den += ex;
    }
    o = acc / den;
  }
  sp[slot * 32 + c] = o;
  __syncthreads();
  if (t < 32) {
    float s = 0.f;
#pragma unroll
    for (int j = 0; j < 8; ++j) s += sp[j * 32 + t];
    partial[(size_t)blockIdx.x * 32 + t] = s;
  }
}

// ---------------- reduce stage: partial[nb][32] -> partial2[128][32] ----------------
// Grid-wide TLP so the column sums are latency-hidden (the single-block version
// of this read was 373 us — 1563 serial vmcnt(0) iterations on one CU).
__global__ __launch_bounds__(256) void reduce_kernel(
    const float* __restrict__ partial, int nb, float* __restrict__ partial2) {
  __shared__ float sp[8 * 32];
  int t = threadIdx.x;
  int slot = t >> 5, c = t & 31;
  int row0 = blockIdx.x * 8 + slot;   // 128 blocks * 8 slots = 1024 row streams
  float s = 0.f;
  for (int i = row0; i < nb; i += 1024) s += partial[(size_t)i * 32 + c];
  sp[slot * 32 + c] = s;
  __syncthreads();
  if (t < 32) {
    float tot = 0.f;
#pragma unroll
    for (int j = 0; j < 8; ++j) tot += sp[j * 32 + t];
    partial2[(size_t)blockIdx.x * 32 + t] = tot;
  }
}

// ---------------- final: pool mean + linear + softmax ----------------
__global__ void final_kernel(const float* __restrict__ partial2, int nb,
                             const float* __restrict__ b2, const float* __restrict__ linW,
                             const float* __restrict__ linb, float* __restrict__ out, int N) {
  __shared__ float sd[256];
  __shared__ float pooled[32];
  int t = threadIdx.x;
  int c = t & 31, g = t >> 5;
  float s = 0.f;
  for (int i = g; i < nb; i += 8) s += partial2[(size_t)i * 32 + c];
  sd[t] = s; __syncthreads();
  if (t < 32) {
    float tot = 0.f;
#pragma unroll
    for (int j = 0; j < 8; ++j) tot += sd[j * 32 + t];
    pooled[t] = tot / (float)N + b2[t];
  }
  __syncthreads();
  if (t == 0) {
    float lg[3];
    for (int j = 0; j < 3; ++j) lg[j] = linb[j];
    for (int cc = 0; cc < 32; ++cc)
      for (int j = 0; j < 3; ++j) lg[j] += pooled[cc] * linW[cc * 3 + j];
    float m = fmaxf(lg[0], fmaxf(lg[1], lg[2]));
    float e0 = __expf(lg[0] - m), e1 = __expf(lg[1] - m), e2 = __expf(lg[2] - m);
    float inv = 1.f / (e0 + e1 + e2);
    out[0] = e0 * inv; out[1] = e1 * inv; out[2] = e2 * inv;
  }
}

extern "C" void kernel_launch(void* const* d_in, const int* in_sizes, int n_in,
                              void* d_out, int out_size, void* d_ws, size_t ws_size,
                              hipStream_t stream) {
  const float* x    = (const float*)d_in[0];
  const void*  eidx = d_in[1];
  const float* W1   = (const float*)d_in[2];
  const float* a1s  = (const float*)d_in[3];
  const float* a1d  = (const float*)d_in[4];
  const float* b1   = (const float*)d_in[5];
  const float* W2   = (const float*)d_in[6];
  const float* a2s  = (const float*)d_in[7];
  const float* a2d  = (const float*)d_in[8];
  const float* b2   = (const float*)d_in[9];
  const float* linW = (const float*)d_in[10];
  const float* linb = (const float*)d_in[11];
  float* out = (float*)d_out;

  const int N = in_sizes[0] / 128;
  const int E = in_sizes[1] / 2;

  char* ws = (char*)d_ws;
  size_t off = 0;
  auto alloc = [&](size_t bytes) -> void* {
    size_t o = off;
    off = align_up(off + bytes, 256);
    return (void*)(ws + o);
  };
  int* cnt    = (int*)alloc((size_t)2 * N * sizeof(int));  // cnt + fill contiguous for one memset
  int* fill   = cnt + N;
  int* flag   = (int*)alloc(sizeof(int));
  int* rowptr = (int*)alloc((size_t)(N + 1) * sizeof(int));
  const int nb1024 = (N + 1023) / 1024;
  int* bsum   = (int*)alloc((size_t)nb1024 * sizeof(int));
  int* csr    = (int*)alloc((size_t)E * sizeof(int));
  float* al1s = (float*)alloc((size_t)N * 4 * sizeof(float));
  float* al1d = (float*)alloc((size_t)N * 4 * sizeof(float));
  float* al2s = (float*)alloc((size_t)N * sizeof(float));
  float* al2d = (float*)alloc((size_t)N * sizeof(float));
  float* h1   = (float*)alloc((size_t)N * 128 * sizeof(float));  // reused as h2 after agg1
  float* hout = (float*)alloc((size_t)N * 128 * sizeof(float));
  const int nAggBlocks = (N + 7) / 8;
  float* partial  = (float*)alloc((size_t)nAggBlocks * 32 * sizeof(float));
  float* partial2 = (float*)alloc((size_t)128 * 32 * sizeof(float));
  float* h2 = h1;  // alias: h1 dead after agg1_kernel

  hipMemsetAsync(cnt, 0, (size_t)2 * N * sizeof(int), stream);
  int ncheck = E < 512 ? E : 512;
  detect_kernel<<<1, 256, 0, stream>>>((const unsigned int*)eidx, ncheck, flag);
  hist_kernel<<<(E + 255) / 256, 256, 0, stream>>>(eidx, flag, E, cnt);
  scan1_kernel<<<nb1024, 256, 0, stream>>>(cnt, bsum, N);
  scan2_kernel<<<1, 1, 0, stream>>>(bsum, nb1024, rowptr, N);
  scan3_kernel<<<nb1024, 256, 0, stream>>>(cnt, bsum, rowptr, N);
  scatter_kernel<<<(E + 255) / 256, 256, 0, stream>>>(eidx, flag, E, rowptr, fill, csr);
  gemm1_kernel<<<(N + 31) / 32, 256, 0, stream>>>(x, W1, a1s, a1d, h1, al1s, al1d, N);
  agg1_kernel<<<(N * 64 + 255) / 256, 256, 0, stream>>>(rowptr, csr, h1, al1s, al1d, b1, hout, N);
  gemm2_kernel<<<(N + 31) / 32, 256, 0, stream>>>(hout, W2, a2s, a2d, h2, al2s, al2d, N);
  agg2_kernel<<<nAggBlocks, 256, 0, stream>>>(rowptr, csr, h2, al2s, al2d, partial, N);
  reduce_kernel<<<128, 256, 0, stream>>>(partial, nAggBlocks, partial2);
  final_kernel<<<1, 256, 0, stream>>>(partial2, 128, b2, linW, linb, out, N);
}

// Round 3
// 551.356 us; speedup vs baseline: 1.7906x; 1.1089x over previous
//
#include <hip/hip_runtime.h>
#include <cstdint>
#include <cstddef>

static inline size_t align_up(size_t v, size_t a) { return (v + a - 1) & ~(a - 1); }

// bf16 pack/unpack (RNE — truncation would leave a systematic bias that
// survives the 100k-node mean-pool; RNE errors cancel there)
__device__ inline unsigned bfpack(float x, float y) {
  unsigned ux = __float_as_uint(x); ux += 0x7FFFu + ((ux >> 16) & 1u);
  unsigned uy = __float_as_uint(y); uy += 0x7FFFu + ((uy >> 16) & 1u);
  return (ux >> 16) | (uy & 0xFFFF0000u);
}
__device__ inline float bf_lo(unsigned u) { return __uint_as_float(u << 16); }
__device__ inline float bf_hi(unsigned u) { return __uint_as_float(u & 0xFFFF0000u); }

// ---------------- edge-index dtype detect (int64 vs int32) ----------------
__global__ void detect_kernel(const unsigned int* e, int n_check, int* flag) {
  __shared__ int bad;
  if (threadIdx.x == 0) bad = 0;
  __syncthreads();
  for (int i = threadIdx.x; i < n_check; i += blockDim.x)
    if (e[2 * i + 1] != 0u) bad = 1;  // benign race, same value
  __syncthreads();
  if (threadIdx.x == 0) *flag = bad ? 0 : 1;  // 1 => int64 layout
}

__device__ inline int load_edge(const void* eidx, int is64, size_t idx) {
  if (is64) return (int)((const long long*)eidx)[idx];
  return ((const int*)eidx)[idx];
}

// ---------------- CSR build ----------------
__global__ void hist_kernel(const void* eidx, const int* flag, int E, int* cnt) {
  int e = blockIdx.x * blockDim.x + threadIdx.x;
  if (e >= E) return;
  int d = load_edge(eidx, *flag, (size_t)E + e);
  atomicAdd(&cnt[d], 1);
}

__global__ void scan1_kernel(const int* cnt, int* bsum, int N) {
  __shared__ int sd[256];
  int b = blockIdx.x, t = threadIdx.x;
  int base = b * 1024;
  int s = 0;
  for (int i = t; i < 1024; i += 256) { int idx = base + i; if (idx < N) s += cnt[idx]; }
  sd[t] = s; __syncthreads();
  for (int off = 128; off > 0; off >>= 1) { if (t < off) sd[t] += sd[t + off]; __syncthreads(); }
  if (t == 0) bsum[b] = sd[0];
}

__global__ void scan2_kernel(int* bsum, int nb, int* rowptr, int N) {
  if (blockIdx.x == 0 && threadIdx.x == 0) {
    int run = 0;
    for (int i = 0; i < nb; ++i) { int v = bsum[i]; bsum[i] = run; run += v; }
    rowptr[N] = run;
  }
}

__global__ void scan3_kernel(const int* cnt, const int* bsum, int* rowptr, int N) {
  __shared__ int sd[256];
  int b = blockIdx.x, t = threadIdx.x;
  int base = b * 1024 + t * 4;
  int v[4]; int s = 0;
#pragma unroll
  for (int j = 0; j < 4; ++j) { int idx = base + j; v[j] = (idx < N) ? cnt[idx] : 0; s += v[j]; }
  sd[t] = s; __syncthreads();
  for (int off = 1; off < 256; off <<= 1) {
    int u = (t >= off) ? sd[t - off] : 0;
    __syncthreads();
    sd[t] += u;
    __syncthreads();
  }
  int run = bsum[b] + (sd[t] - s);  // exclusive prefix
#pragma unroll
  for (int j = 0; j < 4; ++j) {
    int idx = base + j;
    if (idx < N) rowptr[idx] = run;
    run += v[j];
  }
}

__global__ void scatter_kernel(const void* eidx, const int* flag, int E,
                               const int* rowptr, int* fill, int* csr_src) {
  int e = blockIdx.x * blockDim.x + threadIdx.x;
  if (e >= E) return;
  int is64 = *flag;
  int s = load_edge(eidx, is64, (size_t)e);
  int d = load_edge(eidx, is64, (size_t)E + e);
  int pos = rowptr[d] + atomicAdd(&fill[d], 1);
  csr_src[pos] = s;
}

// ---------------- GEMM1: h1 = x @ W1 [N,128]x[128,128] -> bf16-packed, + al1 ----------------
__global__ __launch_bounds__(256) void gemm1_kernel(
    const float* __restrict__ x, const float* __restrict__ W1,
    const float* __restrict__ a1s, const float* __restrict__ a1d,
    unsigned* __restrict__ h1b, float* __restrict__ al_s, float* __restrict__ al_d, int N) {
  __shared__ float sW[128 * 64];   // half of W1: [k][c], 32 KB
  __shared__ float sx[32 * 129];   // 32 rows of x, padded stride
  const int t = threadIdx.x;
  const int row0 = blockIdx.x * 32;
  for (int i = t; i < 32 * 32; i += 256) {
    int r = i >> 5, c4 = (i & 31) * 4;
    float4 v = make_float4(0.f, 0.f, 0.f, 0.f);
    if (row0 + r < N) v = *(const float4*)(x + (size_t)(row0 + r) * 128 + c4);
    float* dst = sx + r * 129 + c4;
    dst[0] = v.x; dst[1] = v.y; dst[2] = v.z; dst[3] = v.w;
  }
  const int tx = t & 15, ty = t >> 4;
  const int r0 = 2 * ty, r1 = 2 * ty + 1;
  for (int half = 0; half < 2; ++half) {
    __syncthreads();
    for (int i = t; i < 128 * 16; i += 256) {
      int k = i >> 4, c4 = (i & 15) * 4;
      *(float4*)(sW + k * 64 + c4) = *(const float4*)(W1 + (size_t)k * 128 + half * 64 + c4);
    }
    __syncthreads();
    float acc0[4] = {0.f, 0.f, 0.f, 0.f}, acc1[4] = {0.f, 0.f, 0.f, 0.f};
#pragma unroll 4
    for (int k = 0; k < 128; ++k) {
      float4 w = *(const float4*)(sW + k * 64 + tx * 4);
      float xa = sx[r0 * 129 + k];
      float xb = sx[r1 * 129 + k];
      acc0[0] += xa * w.x; acc0[1] += xa * w.y; acc0[2] += xa * w.z; acc0[3] += xa * w.w;
      acc1[0] += xb * w.x; acc1[1] += xb * w.y; acc1[2] += xb * w.z; acc1[3] += xb * w.w;
    }
    int col = half * 64 + tx * 4;
    int head = col >> 5;
    float as0 = a1s[col], as1 = a1s[col + 1], as2 = a1s[col + 2], as3 = a1s[col + 3];
    float ad0 = a1d[col], ad1 = a1d[col + 1], ad2 = a1d[col + 2], ad3 = a1d[col + 3];
    int g0 = row0 + r0, g1 = row0 + r1;
    if (g0 < N) {
      uint2 u; u.x = bfpack(acc0[0], acc0[1]); u.y = bfpack(acc0[2], acc0[3]);
      *(uint2*)(h1b + (size_t)g0 * 64 + (col >> 1)) = u;
    }
    if (g1 < N) {
      uint2 u; u.x = bfpack(acc1[0], acc1[1]); u.y = bfpack(acc1[2], acc1[3]);
      *(uint2*)(h1b + (size_t)g1 * 64 + (col >> 1)) = u;
    }
    float ps0 = acc0[0] * as0 + acc0[1] * as1 + acc0[2] * as2 + acc0[3] * as3;
    float pd0 = acc0[0] * ad0 + acc0[1] * ad1 + acc0[2] * ad2 + acc0[3] * ad3;
    float ps1 = acc1[0] * as0 + acc1[1] * as1 + acc1[2] * as2 + acc1[3] * as3;
    float pd1 = acc1[0] * ad0 + acc1[1] * ad1 + acc1[2] * ad2 + acc1[3] * ad3;
#pragma unroll
    for (int off = 1; off < 8; off <<= 1) {
      ps0 += __shfl_xor(ps0, off); pd0 += __shfl_xor(pd0, off);
      ps1 += __shfl_xor(ps1, off); pd1 += __shfl_xor(pd1, off);
    }
    if ((tx & 7) == 0) {
      if (g0 < N) { al_s[(size_t)g0 * 4 + head] = ps0; al_d[(size_t)g0 * 4 + head] = pd0; }
      if (g1 < N) { al_s[(size_t)g1 * 4 + head] = ps1; al_d[(size_t)g1 * 4 + head] = pd1; }
    }
  }
}

// ---------------- Layer-1 aggregate + fused GEMM2 + al2: one wave per dst node ----------------
// The wave holds the node's full 128-dim ELU'd output (2 floats/lane); instead
// of materializing hout (51 MB write + 51 MB read + a dispatch), it round-trips
// through a private 512 B LDS row and multiplies against an LDS-staged W2.
__global__ __launch_bounds__(256) void agg1_fused_kernel(
    const int* __restrict__ rowptr, const int* __restrict__ csr_src,
    const unsigned* __restrict__ h1b, const float* __restrict__ al_s, const float* __restrict__ al_d,
    const float* __restrict__ b1, const float* __restrict__ W2,
    const float* __restrict__ a2s, const float* __restrict__ a2d,
    unsigned* __restrict__ h2b, float* __restrict__ al2s, float* __restrict__ al2d, int N) {
  __shared__ float sW2[128 * 32];  // [k][c], stride 32: lanes read 32 consecutive floats -> 2-way alias, free
  __shared__ float sh[4][128];
  const int t = threadIdx.x;
  for (int i = t; i < 1024; i += 256)
    *(float4*)(sW2 + i * 4) = *(const float4*)(W2 + i * 4);
  __syncthreads();  // only barrier; everything below is wave-local

  int gid = blockIdx.x * blockDim.x + t;
  int d = gid >> 6;
  if (d >= N) return;
  int lane = t & 63;
  int slot = t >> 6;
  int head = lane >> 4;
  float ald = al_d[(size_t)d * 4 + head];
  float accx = 0.f, accy = 0.f, den = 0.f;
  {  // self loop
    float e = al_s[(size_t)d * 4 + head] + ald;
    e = e > 0.f ? e : 0.2f * e;
    float ex = __expf(e);
    unsigned u = h1b[(size_t)d * 64 + lane];
    accx += ex * bf_lo(u); accy += ex * bf_hi(u); den += ex;
  }
  int beg = rowptr[d], end = rowptr[d + 1];
  int i = beg;
  for (; i + 2 <= end; i += 2) {
    int s0 = csr_src[i], s1 = csr_src[i + 1];
    float e0 = al_s[(size_t)s0 * 4 + head] + ald;
    float e1 = al_s[(size_t)s1 * 4 + head] + ald;
    unsigned u0 = h1b[(size_t)s0 * 64 + lane];
    unsigned u1 = h1b[(size_t)s1 * 64 + lane];
    e0 = e0 > 0.f ? e0 : 0.2f * e0;
    e1 = e1 > 0.f ? e1 : 0.2f * e1;
    float ex0 = __expf(e0), ex1 = __expf(e1);
    accx += ex0 * bf_lo(u0) + ex1 * bf_lo(u1);
    accy += ex0 * bf_hi(u0) + ex1 * bf_hi(u1);
    den += ex0 + ex1;
  }
  if (i < end) {
    int s0 = csr_src[i];
    float e0 = al_s[(size_t)s0 * 4 + head] + ald;
    unsigned u0 = h1b[(size_t)s0 * 64 + lane];
    e0 = e0 > 0.f ? e0 : 0.2f * e0;
    float ex0 = __expf(e0);
    accx += ex0 * bf_lo(u0); accy += ex0 * bf_hi(u0); den += ex0;
  }
  float inv = 1.f / den;
  float ox = accx * inv + b1[2 * lane];
  float oy = accy * inv + b1[2 * lane + 1];
  ox = ox > 0.f ? ox : expm1f(ox);  // ELU
  oy = oy > 0.f ? oy : expm1f(oy);

  // ---- fused GEMM2 row: h2[d][c] = sum_k elu_out[k] * W2[k][c] ----
  sh[slot][2 * lane] = ox;
  sh[slot][2 * lane + 1] = oy;
  // wave-local RAW on LDS: compiler inserts lgkmcnt wait; no barrier needed
  int c = lane & 31, halfk = lane >> 5;
  const float* shp = &sh[slot][halfk * 64];
  const float* wp = sW2 + (size_t)(halfk * 64) * 32 + c;
  float a2 = 0.f;
#pragma unroll 8
  for (int k = 0; k < 64; ++k) a2 += shp[k] * wp[k * 32];  // shp: broadcast; wp: conflict-free
  a2 += __shfl_xor(a2, 32);  // combine k-halves; lanes c and c+32 now both hold h2[d][c]
  float partner = __shfl_xor(a2, 1);
  float ps = a2 * a2s[c], pd = a2 * a2d[c];
#pragma unroll
  for (int off = 1; off < 32; off <<= 1) { ps += __shfl_xor(ps, off); pd += __shfl_xor(pd, off); }
  if (lane < 32 && (c & 1) == 0)
    h2b[(size_t)d * 16 + (c >> 1)] = bfpack(a2, partner);
  if (lane == 0) { al2s[d] = ps; al2d[d] = pd; }
}

// ---------------- Layer-2 aggregate + pooled partials: half-wave per node ----------------
__global__ __launch_bounds__(256) void agg2_kernel(
    const int* __restrict__ rowptr, const int* __restrict__ csr_src,
    const unsigned* __restrict__ h2b, const float* __restrict__ al_s, const float* __restrict__ al_d,
    float* __restrict__ partial, int N) {
  __shared__ float sp[8 * 32];
  int t = threadIdx.x;
  int slot = t >> 5;   // 8 nodes per block
  int c = t & 31;
  int node = blockIdx.x * 8 + slot;
  float o = 0.f;
  if (node < N) {
    bool hi = (c & 1) != 0;
    int cw = c >> 1;
    float ald = al_d[node];
    float acc = 0.f, den = 0.f;
    {  // self loop
      float e = al_s[node] + ald;
      e = e > 0.f ? e : 0.2f * e;
      float ex = __expf(e);
      unsigned u = h2b[(size_t)node * 16 + cw];
      acc += ex * (hi ? bf_hi(u) : bf_lo(u)); den += ex;
    }
    int beg = rowptr[node], end = rowptr[node + 1];
    int i = beg;
    for (; i + 2 <= end; i += 2) {
      int s0 = csr_src[i], s1 = csr_src[i + 1];
      float e0 = al_s[s0] + ald;
      float e1 = al_s[s1] + ald;
      unsigned u0 = h2b[(size_t)s0 * 16 + cw];
      unsigned u1 = h2b[(size_t)s1 * 16 + cw];
      e0 = e0 > 0.f ? e0 : 0.2f * e0;
      e1 = e1 > 0.f ? e1 : 0.2f * e1;
      float ex0 = __expf(e0), ex1 = __expf(e1);
      acc += ex0 * (hi ? bf_hi(u0) : bf_lo(u0)) + ex1 * (hi ? bf_hi(u1) : bf_lo(u1));
      den += ex0 + ex1;
    }
    if (i < end) {
      int s0 = csr_src[i];
      float e0 = al_s[s0] + ald;
      unsigned u0 = h2b[(size_t)s0 * 16 + cw];
      e0 = e0 > 0.f ? e0 : 0.2f * e0;
      float ex0 = __expf(e0);
      acc += ex0 * (hi ? bf_hi(u0) : bf_lo(u0));
      den += ex0;
    }
    o = acc / den;
  }
  sp[slot * 32 + c] = o;
  __syncthreads();
  if (t < 32) {
    float s = 0.f;
#pragma unroll
    for (int j = 0; j < 8; ++j) s += sp[j * 32 + t];
    partial[(size_t)blockIdx.x * 32 + t] = s;
  }
}

// ---------------- reduce stage: partial[nb][32] -> partial2[128][32] ----------------
__global__ __launch_bounds__(256) void reduce_kernel(
    const float* __restrict__ partial, int nb, float* __restrict__ partial2) {
  __shared__ float sp[8 * 32];
  int t = threadIdx.x;
  int slot = t >> 5, c = t & 31;
  int row0 = blockIdx.x * 8 + slot;
  float s = 0.f;
  for (int i = row0; i < nb; i += 1024) s += partial[(size_t)i * 32 + c];
  sp[slot * 32 + c] = s;
  __syncthreads();
  if (t < 32) {
    float tot = 0.f;
#pragma unroll
    for (int j = 0; j < 8; ++j) tot += sp[j * 32 + t];
    partial2[(size_t)blockIdx.x * 32 + t] = tot;
  }
}

// ---------------- final: pool mean + linear + softmax ----------------
__global__ void final_kernel(const float* __restrict__ partial2, int nb,
                             const float* __restrict__ b2, const float* __restrict__ linW,
                             const float* __restrict__ linb, float* __restrict__ out, int N) {
  __shared__ float sd[256];
  __shared__ float pooled[32];
  int t = threadIdx.x;
  int c = t & 31, g = t >> 5;
  float s = 0.f;
  for (int i = g; i < nb; i += 8) s += partial2[(size_t)i * 32 + c];
  sd[t] = s; __syncthreads();
  if (t < 32) {
    float tot = 0.f;
#pragma unroll
    for (int j = 0; j < 8; ++j) tot += sd[j * 32 + t];
    pooled[t] = tot / (float)N + b2[t];
  }
  __syncthreads();
  if (t == 0) {
    float lg[3];
    for (int j = 0; j < 3; ++j) lg[j] = linb[j];
    for (int cc = 0; cc < 32; ++cc)
      for (int j = 0; j < 3; ++j) lg[j] += pooled[cc] * linW[cc * 3 + j];
    float m = fmaxf(lg[0], fmaxf(lg[1], lg[2]));
    float e0 = __expf(lg[0] - m), e1 = __expf(lg[1] - m), e2 = __expf(lg[2] - m);
    float inv = 1.f / (e0 + e1 + e2);
    out[0] = e0 * inv; out[1] = e1 * inv; out[2] = e2 * inv;
  }
}

extern "C" void kernel_launch(void* const* d_in, const int* in_sizes, int n_in,
                              void* d_out, int out_size, void* d_ws, size_t ws_size,
                              hipStream_t stream) {
  const float* x    = (const float*)d_in[0];
  const void*  eidx = d_in[1];
  const float* W1   = (const float*)d_in[2];
  const float* a1s  = (const float*)d_in[3];
  const float* a1d  = (const float*)d_in[4];
  const float* b1   = (const float*)d_in[5];
  const float* W2   = (const float*)d_in[6];
  const float* a2s  = (const float*)d_in[7];
  const float* a2d  = (const float*)d_in[8];
  const float* b2   = (const float*)d_in[9];
  const float* linW = (const float*)d_in[10];
  const float* linb = (const float*)d_in[11];
  float* out = (float*)d_out;

  const int N = in_sizes[0] / 128;
  const int E = in_sizes[1] / 2;

  char* ws = (char*)d_ws;
  size_t off = 0;
  auto alloc = [&](size_t bytes) -> void* {
    size_t o = off;
    off = align_up(off + bytes, 256);
    return (void*)(ws + o);
  };
  int* cnt    = (int*)alloc((size_t)2 * N * sizeof(int));  // cnt + fill contiguous for one memset
  int* fill   = cnt + N;
  int* flag   = (int*)alloc(sizeof(int));
  int* rowptr = (int*)alloc((size_t)(N + 1) * sizeof(int));
  const int nb1024 = (N + 1023) / 1024;
  int* bsum   = (int*)alloc((size_t)nb1024 * sizeof(int));
  int* csr    = (int*)alloc((size_t)E * sizeof(int));
  float* al1s = (float*)alloc((size_t)N * 4 * sizeof(float));
  float* al1d = (float*)alloc((size_t)N * 4 * sizeof(float));
  float* al2s = (float*)alloc((size_t)N * sizeof(float));
  float* al2d = (float*)alloc((size_t)N * sizeof(float));
  unsigned* h1b = (unsigned*)alloc((size_t)N * 64 * sizeof(unsigned));  // bf16-packed [N][128]
  unsigned* h2b = (unsigned*)alloc((size_t)N * 16 * sizeof(unsigned));  // bf16-packed [N][32]
  const int nAggBlocks = (N + 7) / 8;
  float* partial  = (float*)alloc((size_t)nAggBlocks * 32 * sizeof(float));
  float* partial2 = (float*)alloc((size_t)128 * 32 * sizeof(float));

  hipMemsetAsync(cnt, 0, (size_t)2 * N * sizeof(int), stream);
  int ncheck = E < 512 ? E : 512;
  detect_kernel<<<1, 256, 0, stream>>>((const unsigned int*)eidx, ncheck, flag);
  hist_kernel<<<(E + 255) / 256, 256, 0, stream>>>(eidx, flag, E, cnt);
  scan1_kernel<<<nb1024, 256, 0, stream>>>(cnt, bsum, N);
  scan2_kernel<<<1, 1, 0, stream>>>(bsum, nb1024, rowptr, N);
  scan3_kernel<<<nb1024, 256, 0, stream>>>(cnt, bsum, rowptr, N);
  scatter_kernel<<<(E + 255) / 256, 256, 0, stream>>>(eidx, flag, E, rowptr, fill, csr);
  gemm1_kernel<<<(N + 31) / 32, 256, 0, stream>>>(x, W1, a1s, a1d, h1b, al1s, al1d, N);
  agg1_fused_kernel<<<(N * 64 + 255) / 256, 256, 0, stream>>>(
      rowptr, csr, h1b, al1s, al1d, b1, W2, a2s, a2d, h2b, al2s, al2d, N);
  agg2_kernel<<<nAggBlocks, 256, 0, stream>>>(rowptr, csr, h2b, al2s, al2d, partial, N);
  reduce_kernel<<<128, 256, 0, stream>>>(partial, nAggBlocks, partial2);
  final_kernel<<<1, 256, 0, stream>>>(partial2, 128, b2, linW, linb, out, N);
}

// Round 4
// 435.759 us; speedup vs baseline: 2.2656x; 1.2653x over previous
//
#include <hip/hip_runtime.h>
#include <cstdint>
#include <cstddef>

static inline size_t align_up(size_t v, size_t a) { return (v + a - 1) & ~(a - 1); }

typedef __attribute__((ext_vector_type(8))) short short8;
typedef __attribute__((ext_vector_type(4))) float f32x4;

// bf16 helpers (RNE — unbiased so errors cancel in the 100k-node mean-pool)
__device__ inline unsigned short bf16_1(float x) {
  unsigned u = __float_as_uint(x);
  u += 0x7FFFu + ((u >> 16) & 1u);
  return (unsigned short)(u >> 16);
}
__device__ inline unsigned bfpack(float x, float y) {
  unsigned ux = __float_as_uint(x); ux += 0x7FFFu + ((ux >> 16) & 1u);
  unsigned uy = __float_as_uint(y); uy += 0x7FFFu + ((uy >> 16) & 1u);
  return (ux >> 16) | (uy & 0xFFFF0000u);
}
__device__ inline float bf_lo(unsigned u) { return __uint_as_float(u << 16); }
__device__ inline float bf_hi(unsigned u) { return __uint_as_float(u & 0xFFFF0000u); }

// ---------------- edge-index dtype detect (int64 vs int32) ----------------
__global__ void detect_kernel(const unsigned int* e, int n_check, int* flag) {
  __shared__ int bad;
  if (threadIdx.x == 0) bad = 0;
  __syncthreads();
  for (int i = threadIdx.x; i < n_check; i += blockDim.x)
    if (e[2 * i + 1] != 0u) bad = 1;  // benign race, same value
  __syncthreads();
  if (threadIdx.x == 0) *flag = bad ? 0 : 1;  // 1 => int64 layout
}

__device__ inline int load_edge(const void* eidx, int is64, size_t idx) {
  if (is64) return (int)((const long long*)eidx)[idx];
  return ((const int*)eidx)[idx];
}

// ---------------- weight prep: transpose to [c][k] bf16 ----------------
__global__ void prep_kernel(const float* __restrict__ W1, const float* __restrict__ W2,
                            unsigned short* __restrict__ w1t, unsigned short* __restrict__ w2t) {
  int t = blockIdx.x * 256 + threadIdx.x;
  if (t < 16384) {
    int c = t >> 7, k = t & 127;
    w1t[t] = bf16_1(W1[(size_t)k * 128 + c]);
  } else if (t < 20480) {
    int i = t - 16384;
    int c = i >> 7, k = i & 127;
    w2t[i] = bf16_1(W2[(size_t)k * 32 + c]);
  }
}

// ---------------- CSR build ----------------
__global__ void hist_kernel(const void* eidx, const int* flag, int E, int* cnt) {
  int e = blockIdx.x * blockDim.x + threadIdx.x;
  if (e >= E) return;
  int d = load_edge(eidx, *flag, (size_t)E + e);
  atomicAdd(&cnt[d], 1);
}

__global__ void scan1_kernel(const int* cnt, int* bsum, int N) {
  __shared__ int sd[256];
  int b = blockIdx.x, t = threadIdx.x;
  int base = b * 1024;
  int s = 0;
  for (int i = t; i < 1024; i += 256) { int idx = base + i; if (idx < N) s += cnt[idx]; }
  sd[t] = s; __syncthreads();
  for (int off = 128; off > 0; off >>= 1) { if (t < off) sd[t] += sd[t + off]; __syncthreads(); }
  if (t == 0) bsum[b] = sd[0];
}

// parallel replacement for the serial scan2 (98 dependent global loads ~25us)
__global__ void scan2b_kernel(int* bsum, int nb, int* rowptr, int N) {
  __shared__ int sd[256];
  int t = threadIdx.x;
  int v = (t < nb) ? bsum[t] : 0;
  sd[t] = v; __syncthreads();
  for (int off = 1; off < 256; off <<= 1) {
    int u = (t >= off) ? sd[t - off] : 0;
    __syncthreads();
    sd[t] += u;
    __syncthreads();
  }
  if (t < nb) bsum[t] = sd[t] - v;      // exclusive prefix
  if (t == nb - 1) rowptr[N] = sd[t];   // total edge count
}

__global__ void scan3_kernel(const int* cnt, const int* bsum, int* rowptr, int N) {
  __shared__ int sd[256];
  int b = blockIdx.x, t = threadIdx.x;
  int base = b * 1024 + t * 4;
  int v[4]; int s = 0;
#pragma unroll
  for (int j = 0; j < 4; ++j) { int idx = base + j; v[j] = (idx < N) ? cnt[idx] : 0; s += v[j]; }
  sd[t] = s; __syncthreads();
  for (int off = 1; off < 256; off <<= 1) {
    int u = (t >= off) ? sd[t - off] : 0;
    __syncthreads();
    sd[t] += u;
    __syncthreads();
  }
  int run = bsum[b] + (sd[t] - s);  // exclusive prefix
#pragma unroll
  for (int j = 0; j < 4; ++j) {
    int idx = base + j;
    if (idx < N) rowptr[idx] = run;
    run += v[j];
  }
}

__global__ void scatter_kernel(const void* eidx, const int* flag, int E,
                               const int* rowptr, int* fill, int* csr_src) {
  int e = blockIdx.x * blockDim.x + threadIdx.x;
  if (e >= E) return;
  int is64 = *flag;
  int s = load_edge(eidx, is64, (size_t)e);
  int d = load_edge(eidx, is64, (size_t)E + e);
  int pos = rowptr[d] + atomicAdd(&fill[d], 1);
  csr_src[pos] = s;
}

// ---------------- GEMM1 (MFMA bf16): h1 = bf16(x) @ bf16(W1) [N,128]x[128,128] ----------------
// A-frag layout (16x16x32): A[m=lane&15][k=quad*8+j]; B[k=quad*8+j][n=lane&15];
// C/D: col=lane&15, row=quad*4+reg. Tiles padded to stride 136 (16B-aligned, <=2-way banks).
__global__ __launch_bounds__(256) void gemm1_mfma(
    const float* __restrict__ x, const unsigned short* __restrict__ w1t,
    unsigned short* __restrict__ h1u, int N) {
  __shared__ unsigned short sx[64 * 136];
  __shared__ unsigned short sw[128 * 136];
  const int t = threadIdx.x;
  const int row0 = blockIdx.x * 64;
  for (int i = t; i < 4096; i += 256) {          // W1^T bf16, ushort4 units
    int c = i >> 5, k4 = (i & 31) * 4;
    *(ushort4*)&sw[c * 136 + k4] = *(const ushort4*)&w1t[c * 128 + k4];
  }
  for (int i = t; i < 2048; i += 256) {          // x tile fp32 -> bf16, float4 units
    int r = i >> 5, c4 = (i & 31) * 4;
    float4 v = make_float4(0.f, 0.f, 0.f, 0.f);
    if (row0 + r < N) v = *(const float4*)(x + (size_t)(row0 + r) * 128 + c4);
    ushort4 b; b.x = bf16_1(v.x); b.y = bf16_1(v.y); b.z = bf16_1(v.z); b.w = bf16_1(v.w);
    *(ushort4*)&sx[r * 136 + c4] = b;
  }
  __syncthreads();
  const int lane = t & 63, wave = t >> 6;
  const int m = lane & 15, quad = lane >> 4;
  const unsigned short* arow = &sx[(wave * 16 + m) * 136];
  short8 A[4];
#pragma unroll
  for (int ks = 0; ks < 4; ++ks) A[ks] = *(const short8*)&arow[ks * 32 + quad * 8];
  const int g = row0 + wave * 16 + quad * 4;
#pragma unroll
  for (int nt = 0; nt < 8; ++nt) {
    const unsigned short* brow = &sw[(nt * 16 + m) * 136];
    f32x4 acc = {0.f, 0.f, 0.f, 0.f};
#pragma unroll
    for (int ks = 0; ks < 4; ++ks) {
      short8 B = *(const short8*)&brow[ks * 32 + quad * 8];
      acc = __builtin_amdgcn_mfma_f32_16x16x32_bf16(A[ks], B, acc, 0, 0, 0);
    }
    int col = nt * 16 + m;
#pragma unroll
    for (int r = 0; r < 4; ++r) {
      int gr = g + r;
      if (gr < N) h1u[(size_t)gr * 128 + col] = bf16_1(acc[r]);
    }
  }
}

// ---------------- GEMM2 (MFMA bf16): h2 = houtb @ bf16(W2) [N,128]x[128,32] ----------------
__global__ __launch_bounds__(256) void gemm2_mfma(
    const unsigned* __restrict__ houtb, const unsigned short* __restrict__ w2t,
    unsigned short* __restrict__ h2u, int N) {
  __shared__ unsigned short sx[64 * 136];
  __shared__ unsigned short sw[32 * 136];
  const int t = threadIdx.x;
  const int row0 = blockIdx.x * 64;
  for (int i = t; i < 1024; i += 256) {          // W2^T bf16
    int c = i >> 5, k4 = (i & 31) * 4;
    *(ushort4*)&sw[c * 136 + k4] = *(const ushort4*)&w2t[c * 128 + k4];
  }
  for (int i = t; i < 2048; i += 256) {          // houtb already bf16: uint2 units
    int r = i >> 5, d2 = (i & 31) * 2;
    uint2 v = make_uint2(0u, 0u);
    if (row0 + r < N) v = *(const uint2*)(houtb + (size_t)(row0 + r) * 64 + d2);
    *(uint2*)&sx[r * 136 + d2 * 2] = v;
  }
  __syncthreads();
  const int lane = t & 63, wave = t >> 6;
  const int m = lane & 15, quad = lane >> 4;
  const unsigned short* arow = &sx[(wave * 16 + m) * 136];
  short8 A[4];
#pragma unroll
  for (int ks = 0; ks < 4; ++ks) A[ks] = *(const short8*)&arow[ks * 32 + quad * 8];
  const int g = row0 + wave * 16 + quad * 4;
#pragma unroll
  for (int nt = 0; nt < 2; ++nt) {
    const unsigned short* brow = &sw[(nt * 16 + m) * 136];
    f32x4 acc = {0.f, 0.f, 0.f, 0.f};
#pragma unroll
    for (int ks = 0; ks < 4; ++ks) {
      short8 B = *(const short8*)&brow[ks * 32 + quad * 8];
      acc = __builtin_amdgcn_mfma_f32_16x16x32_bf16(A[ks], B, acc, 0, 0, 0);
    }
    int col = nt * 16 + m;
#pragma unroll
    for (int r = 0; r < 4; ++r) {
      int gr = g + r;
      if (gr < N) h2u[(size_t)gr * 32 + col] = bf16_1(acc[r]);
    }
  }
}

// ---------------- al1: attention logits from bf16 h1 (one wave per node) ----------------
__global__ __launch_bounds__(256) void al1_kernel(
    const unsigned* __restrict__ h1b, const float* __restrict__ a1s, const float* __restrict__ a1d,
    float* __restrict__ al_s, float* __restrict__ al_d, int N) {
  int t = threadIdx.x;
  int n = (blockIdx.x * 256 + t) >> 6;
  if (n >= N) return;
  int lane = t & 63;
  unsigned u = h1b[(size_t)n * 64 + lane];
  float lo = bf_lo(u), hi = bf_hi(u);
  int c = 2 * lane;
  float ps = lo * a1s[c] + hi * a1s[c + 1];
  float pd = lo * a1d[c] + hi * a1d[c + 1];
#pragma unroll
  for (int off = 1; off < 16; off <<= 1) { ps += __shfl_xor(ps, off); pd += __shfl_xor(pd, off); }
  if ((lane & 15) == 0) {
    al_s[(size_t)n * 4 + (lane >> 4)] = ps;
    al_d[(size_t)n * 4 + (lane >> 4)] = pd;
  }
}

// ---------------- al2: 16 lanes per node ----------------
__global__ __launch_bounds__(256) void al2_kernel(
    const unsigned* __restrict__ h2b, const float* __restrict__ a2s, const float* __restrict__ a2d,
    float* __restrict__ al_s, float* __restrict__ al_d, int N) {
  int t = threadIdx.x;
  int n = (blockIdx.x * 256 + t) >> 4;
  if (n >= N) return;
  int l = t & 15;
  unsigned u = h2b[(size_t)n * 16 + l];
  float lo = bf_lo(u), hi = bf_hi(u);
  int c = 2 * l;
  float ps = lo * a2s[c] + hi * a2s[c + 1];
  float pd = lo * a2d[c] + hi * a2d[c + 1];
#pragma unroll
  for (int off = 1; off < 16; off <<= 1) { ps += __shfl_xor(ps, off); pd += __shfl_xor(pd, off); }
  if (l == 0) { al_s[n] = ps; al_d[n] = pd; }
}

// ---------------- Layer-1 aggregate: one wave per dst node, 8-edge groups ----------------
// Exp-dedup: lanes compute 32 distinct (edge,head) exps per group (was: 64 lanes x
// redundant exp per edge), distributed via shfl; 8 gathers in flight.
__global__ __launch_bounds__(256) void agg1_kernel(
    const int* __restrict__ rowptr, const int* __restrict__ csr_src,
    const unsigned* __restrict__ h1b, const float* __restrict__ al_s, const float* __restrict__ al_d,
    const float* __restrict__ b1, unsigned* __restrict__ houtb, int N) {
  int t = threadIdx.x;
  int d = (blockIdx.x * 256 + t) >> 6;
  if (d >= N) return;
  int lane = t & 63;
  int head = lane >> 4;   // head for my feature pair (cols 2*lane, 2*lane+1)
  int he = lane & 3;      // head for my exp-phase combo
  float ald_h = al_d[(size_t)d * 4 + head];
  float ald_e = al_d[(size_t)d * 4 + he];
  float accx, accy, den;
  {  // self loop
    float e = al_s[(size_t)d * 4 + head] + ald_h;
    e = fmaxf(e, 0.2f * e);
    float ex = __expf(e);
    unsigned u = h1b[(size_t)d * 64 + lane];
    accx = ex * bf_lo(u); accy = ex * bf_hi(u); den = ex;
  }
  int beg = rowptr[d], end = rowptr[d + 1];
  for (int i = beg; i < end; i += 8) {
    int idx = i + ((lane >> 2) & 7);                 // edge slot for my combo
    int sj = (idx < end) ? csr_src[idx] : d;
    float e = al_s[(size_t)sj * 4 + he] + ald_e;
    e = fmaxf(e, 0.2f * e);
    float ex = __expf(e);
    if (idx >= end) ex = 0.f;                        // mask tail: contributes nothing
#pragma unroll
    for (int j = 0; j < 8; ++j) {
      int s = __shfl(sj, j * 4);                     // uniform index -> readlane
      float exj = __shfl(ex, j * 4 + head);          // bpermute
      unsigned u = h1b[(size_t)s * 64 + lane];
      accx += exj * bf_lo(u);
      accy += exj * bf_hi(u);
      den += exj;
    }
  }
  float inv = 1.f / den;
  float ox = accx * inv + b1[2 * lane];
  float oy = accy * inv + b1[2 * lane + 1];
  ox = ox > 0.f ? ox : expm1f(ox);  // ELU
  oy = oy > 0.f ? oy : expm1f(oy);
  houtb[(size_t)d * 64 + lane] = bfpack(ox, oy);
}

// ---------------- Layer-2 aggregate + pooled partials: half-wave per node, 8-edge groups ----------------
__global__ __launch_bounds__(256) void agg2_kernel(
    const int* __restrict__ rowptr, const int* __restrict__ csr_src,
    const unsigned* __restrict__ h2b, const float* __restrict__ al_s, const float* __restrict__ al_d,
    float* __restrict__ partial, int N) {
  __shared__ float sp[8 * 32];
  int t = threadIdx.x;
  int lane = t & 63;
  int slot = t >> 5;
  int c = t & 31;
  int node = blockIdx.x * 8 + slot;
  float o = 0.f;
  if (node < N) {
    int cw = c >> 1;
    int sh_amt = (c & 1) ? 0 : 16;
    float ald = al_d[node];
    float acc = 0.f, den = 0.f;
    {  // self loop
      float e = al_s[node] + ald;
      e = fmaxf(e, 0.2f * e);
      float ex = __expf(e);
      unsigned u = h2b[(size_t)node * 16 + cw];
      acc += ex * __uint_as_float((u << sh_amt) & 0xFFFF0000u);
      den += ex;
    }
    int beg = rowptr[node], end = rowptr[node + 1];
    for (int i = beg; i < end; i += 8) {
      int idx = i + (lane & 7);
      int sj = (idx < end) ? csr_src[idx] : node;
      float e = al_s[sj] + ald;
      e = fmaxf(e, 0.2f * e);
      float ex = __expf(e);
      if (idx >= end) ex = 0.f;
#pragma unroll
      for (int j = 0; j < 8; ++j) {
        int lsrc = (lane & 32) | j;                  // stay within my half-wave
        int s = __shfl(sj, lsrc);
        float exj = __shfl(ex, lsrc);
        unsigned u = h2b[(size_t)s * 16 + cw];
        acc += exj * __uint_as_float((u << sh_amt) & 0xFFFF0000u);
        den += exj;
      }
    }
    o = acc / den;
  }
  sp[slot * 32 + c] = o;
  __syncthreads();
  if (t < 32) {
    float s = 0.f;
#pragma unroll
    for (int j = 0; j < 8; ++j) s += sp[j * 32 + t];
    partial[(size_t)blockIdx.x * 32 + t] = s;
  }
}

// ---------------- reduce stage: partial[nb][32] -> partial2[128][32] ----------------
__global__ __launch_bounds__(256) void reduce_kernel(
    const float* __restrict__ partial, int nb, float* __restrict__ partial2) {
  __shared__ float sp[8 * 32];
  int t = threadIdx.x;
  int slot = t >> 5, c = t & 31;
  int row0 = blockIdx.x * 8 + slot;
  float s = 0.f;
  for (int i = row0; i < nb; i += 1024) s += partial[(size_t)i * 32 + c];
  sp[slot * 32 + c] = s;
  __syncthreads();
  if (t < 32) {
    float tot = 0.f;
#pragma unroll
    for (int j = 0; j < 8; ++j) tot += sp[j * 32 + t];
    partial2[(size_t)blockIdx.x * 32 + t] = tot;
  }
}

// ---------------- final: pool mean + linear + softmax ----------------
__global__ void final_kernel(const float* __restrict__ partial2, int nb,
                             const float* __restrict__ b2, const float* __restrict__ linW,
                             const float* __restrict__ linb, float* __restrict__ out, int N) {
  __shared__ float sd[256];
  __shared__ float pooled[32];
  int t = threadIdx.x;
  int c = t & 31, g = t >> 5;
  float s = 0.f;
  for (int i = g; i < nb; i += 8) s += partial2[(size_t)i * 32 + c];
  sd[t] = s; __syncthreads();
  if (t < 32) {
    float tot = 0.f;
#pragma unroll
    for (int j = 0; j < 8; ++j) tot += sd[j * 32 + t];
    pooled[t] = tot / (float)N + b2[t];
  }
  __syncthreads();
  if (t == 0) {
    float lg[3];
    for (int j = 0; j < 3; ++j) lg[j] = linb[j];
    for (int cc = 0; cc < 32; ++cc)
      for (int j = 0; j < 3; ++j) lg[j] += pooled[cc] * linW[cc * 3 + j];
    float m = fmaxf(lg[0], fmaxf(lg[1], lg[2]));
    float e0 = __expf(lg[0] - m), e1 = __expf(lg[1] - m), e2 = __expf(lg[2] - m);
    float inv = 1.f / (e0 + e1 + e2);
    out[0] = e0 * inv; out[1] = e1 * inv; out[2] = e2 * inv;
  }
}

extern "C" void kernel_launch(void* const* d_in, const int* in_sizes, int n_in,
                              void* d_out, int out_size, void* d_ws, size_t ws_size,
                              hipStream_t stream) {
  const float* x    = (const float*)d_in[0];
  const void*  eidx = d_in[1];
  const float* W1   = (const float*)d_in[2];
  const float* a1s  = (const float*)d_in[3];
  const float* a1d  = (const float*)d_in[4];
  const float* b1   = (const float*)d_in[5];
  const float* W2   = (const float*)d_in[6];
  const float* a2s  = (const float*)d_in[7];
  const float* a2d  = (const float*)d_in[8];
  const float* b2   = (const float*)d_in[9];
  const float* linW = (const float*)d_in[10];
  const float* linb = (const float*)d_in[11];
  float* out = (float*)d_out;

  const int N = in_sizes[0] / 128;
  const int E = in_sizes[1] / 2;

  char* ws = (char*)d_ws;
  size_t off = 0;
  auto alloc = [&](size_t bytes) -> void* {
    size_t o = off;
    off = align_up(off + bytes, 256);
    return (void*)(ws + o);
  };
  int* cnt    = (int*)alloc((size_t)2 * N * sizeof(int));  // cnt + fill contiguous for one memset
  int* fill   = cnt + N;
  int* flag   = (int*)alloc(sizeof(int));
  int* rowptr = (int*)alloc((size_t)(N + 1) * sizeof(int));
  const int nb1024 = (N + 1023) / 1024;
  int* bsum   = (int*)alloc((size_t)nb1024 * sizeof(int));
  int* csr    = (int*)alloc((size_t)E * sizeof(int));
  float* al1s = (float*)alloc((size_t)N * 4 * sizeof(float));
  float* al1d = (float*)alloc((size_t)N * 4 * sizeof(float));
  float* al2s = (float*)alloc((size_t)N * sizeof(float));
  float* al2d = (float*)alloc((size_t)N * sizeof(float));
  unsigned short* w1t = (unsigned short*)alloc(16384 * sizeof(unsigned short));
  unsigned short* w2t = (unsigned short*)alloc(4096 * sizeof(unsigned short));
  unsigned* h1b   = (unsigned*)alloc((size_t)N * 64 * sizeof(unsigned));  // bf16 [N][128]
  unsigned* houtb = (unsigned*)alloc((size_t)N * 64 * sizeof(unsigned));  // bf16 ELU'd layer-1 out
  unsigned* h2b   = (unsigned*)alloc((size_t)N * 16 * sizeof(unsigned));  // bf16 [N][32]
  const int nAggBlocks = (N + 7) / 8;
  float* partial  = (float*)alloc((size_t)nAggBlocks * 32 * sizeof(float));
  float* partial2 = (float*)alloc((size_t)128 * 32 * sizeof(float));

  hipMemsetAsync(cnt, 0, (size_t)2 * N * sizeof(int), stream);
  int ncheck = E < 512 ? E : 512;
  detect_kernel<<<1, 256, 0, stream>>>((const unsigned int*)eidx, ncheck, flag);
  prep_kernel<<<80, 256, 0, stream>>>(W1, W2, w1t, w2t);
  hist_kernel<<<(E + 255) / 256, 256, 0, stream>>>(eidx, flag, E, cnt);
  scan1_kernel<<<nb1024, 256, 0, stream>>>(cnt, bsum, N);
  scan2b_kernel<<<1, 256, 0, stream>>>(bsum, nb1024, rowptr, N);
  scan3_kernel<<<nb1024, 256, 0, stream>>>(cnt, bsum, rowptr, N);
  scatter_kernel<<<(E + 255) / 256, 256, 0, stream>>>(eidx, flag, E, rowptr, fill, csr);

  const int gemmBlocks = (N + 63) / 64;
  gemm1_mfma<<<gemmBlocks, 256, 0, stream>>>(x, w1t, (unsigned short*)h1b, N);
  al1_kernel<<<(N * 64 + 255) / 256, 256, 0, stream>>>(h1b, a1s, a1d, al1s, al1d, N);
  agg1_kernel<<<(N * 64 + 255) / 256, 256, 0, stream>>>(rowptr, csr, h1b, al1s, al1d, b1, houtb, N);
  gemm2_mfma<<<gemmBlocks, 256, 0, stream>>>(houtb, w2t, (unsigned short*)h2b, N);
  al2_kernel<<<(N * 16 + 255) / 256, 256, 0, stream>>>(h2b, a2s, a2d, al2s, al2d, N);
  agg2_kernel<<<nAggBlocks, 256, 0, stream>>>(rowptr, csr, h2b, al2s, al2d, partial, N);
  reduce_kernel<<<128, 256, 0, stream>>>(partial, nAggBlocks, partial2);
  final_kernel<<<1, 256, 0, stream>>>(partial2, 128, b2, linW, linb, out, N);
}

// Round 5
// 338.179 us; speedup vs baseline: 2.9194x; 1.2885x over previous
//
#include <hip/hip_runtime.h>
#include <cstdint>
#include <cstddef>

static inline size_t align_up(size_t v, size_t a) { return (v + a - 1) & ~(a - 1); }

typedef __attribute__((ext_vector_type(8))) short short8;
typedef __attribute__((ext_vector_type(4))) float f32x4;

// bf16 helpers (RNE — unbiased so errors cancel in the 100k-node mean-pool)
__device__ inline unsigned short bf16_1(float x) {
  unsigned u = __float_as_uint(x);
  u += 0x7FFFu + ((u >> 16) & 1u);
  return (unsigned short)(u >> 16);
}
__device__ inline unsigned bfpack(float x, float y) {
  unsigned ux = __float_as_uint(x); ux += 0x7FFFu + ((ux >> 16) & 1u);
  unsigned uy = __float_as_uint(y); uy += 0x7FFFu + ((uy >> 16) & 1u);
  return (ux >> 16) | (uy & 0xFFFF0000u);
}
__device__ inline float bf_lo(unsigned u) { return __uint_as_float(u << 16); }
__device__ inline float bf_hi(unsigned u) { return __uint_as_float(u & 0xFFFF0000u); }

// ---------------- edge-index dtype detect (int64 vs int32) ----------------
__global__ void detect_kernel(const unsigned int* e, int n_check, int* flag) {
  __shared__ int bad;
  if (threadIdx.x == 0) bad = 0;
  __syncthreads();
  for (int i = threadIdx.x; i < n_check; i += blockDim.x)
    if (e[2 * i + 1] != 0u) bad = 1;  // benign race, same value
  __syncthreads();
  if (threadIdx.x == 0) *flag = bad ? 0 : 1;  // 1 => int64 layout
}

__device__ inline int load_edge(const void* eidx, int is64, size_t idx) {
  if (is64) return (int)((const long long*)eidx)[idx];
  return ((const int*)eidx)[idx];
}

// ---------------- weight prep: transpose to [c][k] bf16 ----------------
__global__ void prep_kernel(const float* __restrict__ W1, const float* __restrict__ W2,
                            unsigned short* __restrict__ w1t, unsigned short* __restrict__ w2t) {
  int t = blockIdx.x * 256 + threadIdx.x;
  if (t < 16384) {
    int c = t >> 7, k = t & 127;
    w1t[t] = bf16_1(W1[(size_t)k * 128 + c]);
  } else if (t < 20480) {
    int i = t - 16384;
    int c = i >> 7, k = i & 127;
    w2t[i] = bf16_1(W2[(size_t)k * 32 + c]);
  }
}

// ======= CSR build via 128-node-bucket counting sort =======
// Old atomic-scatter wrote 107 MB to HBM for 6.4 MB of payload (random 4B
// stores -> full-line writebacks across 8 non-coherent XCD L2s). The bucketed
// path keeps all random writes inside ~8 KB windows.

// ---- stage 1: bucket histogram (bucket = dst >> 7) ----
__global__ __launch_bounds__(256) void bhist_kernel(const void* eidx, const int* flag, int E,
                                                    int* __restrict__ bcnt, int NB) {
  __shared__ int h[1024];
  int t = threadIdx.x;
  for (int i = t; i < 1024; i += 256) h[i] = 0;
  __syncthreads();
  int is64 = *flag;
  for (int i = blockIdx.x * 256 + t; i < E; i += gridDim.x * 256) {
    int d = load_edge(eidx, is64, (size_t)E + i);
    atomicAdd(&h[d >> 7], 1);
  }
  __syncthreads();
  for (int b = t; b < NB; b += 256)
    if (h[b]) atomicAdd(&bcnt[b], h[b]);
}

// ---- stage 2: exclusive scan of bucket counts (NB <= 1024, one block) ----
__global__ void scanB_kernel(const int* __restrict__ bcnt, int* __restrict__ bstart, int NB) {
  __shared__ int sd[256];
  int t = threadIdx.x;
  int base = t * 4;
  int v[4]; int s = 0;
#pragma unroll
  for (int j = 0; j < 4; ++j) { int idx = base + j; v[j] = (idx < NB) ? bcnt[idx] : 0; s += v[j]; }
  sd[t] = s; __syncthreads();
  for (int off = 1; off < 256; off <<= 1) {
    int u = (t >= off) ? sd[t - off] : 0;
    __syncthreads();
    sd[t] += u;
    __syncthreads();
  }
  int run = sd[t] - s;
#pragma unroll
  for (int j = 0; j < 4; ++j) {
    int idx = base + j;
    if (idx < NB) bstart[idx] = run;
    run += v[j];
  }
  if (t == 255) bstart[NB] = sd[255];
}

// ---- stage 3: block-level counting sort of 2048-edge chunks into bucket regions ----
// packed entry: src | (dst&127)<<20   (src < 2^20)
__global__ __launch_bounds__(256) void sortA_kernel(const void* eidx, const int* flag, int E,
                                                    const int* __restrict__ bstart,
                                                    int* __restrict__ fillB,
                                                    unsigned* __restrict__ packed, int NB) {
  __shared__ int hist[1024];
  __shared__ int loff[1024];
  __shared__ int lbase[1024];
  __shared__ int lcnt[1024];
  __shared__ unsigned sortedV[2048];
  __shared__ unsigned short sortedB[2048];
  const int t = threadIdx.x;
  const int chunk0 = blockIdx.x * 2048;
  const int cntE = min(2048, E - chunk0);
  const int is64 = *flag;
  for (int i = t; i < 1024; i += 256) { hist[i] = 0; lcnt[i] = 0; }
  __syncthreads();
  // pass 1: count
  for (int li = t; li < cntE; li += 256) {
    int d = load_edge(eidx, is64, (size_t)E + chunk0 + li);
    atomicAdd(&hist[d >> 7], 1);
  }
  __syncthreads();
  // reserve global space per bucket
  for (int b = t; b < NB; b += 256) {
    int h = hist[b];
    if (h) lbase[b] = bstart[b] + atomicAdd(&fillB[b], h);
  }
  // exclusive scan of hist -> loff (1024 entries, 4/thread)
  {
    int base = t * 4;
    int v[4]; int s = 0;
    __shared__ int sd[256];
#pragma unroll
    for (int j = 0; j < 4; ++j) { v[j] = hist[base + j]; s += v[j]; }
    sd[t] = s; __syncthreads();
    for (int off = 1; off < 256; off <<= 1) {
      int u = (t >= off) ? sd[t - off] : 0;
      __syncthreads();
      sd[t] += u;
      __syncthreads();
    }
    int run = sd[t] - s;
#pragma unroll
    for (int j = 0; j < 4; ++j) { loff[base + j] = run; run += v[j]; }
  }
  __syncthreads();
  // pass 2: place into LDS-sorted order
  for (int li = t; li < cntE; li += 256) {
    int s = load_edge(eidx, is64, (size_t)chunk0 + li);
    int d = load_edge(eidx, is64, (size_t)E + chunk0 + li);
    int b = d >> 7;
    int r = atomicAdd(&lcnt[b], 1);
    int pos = loff[b] + r;
    sortedV[pos] = (unsigned)s | ((unsigned)(d & 127) << 20);
    sortedB[pos] = (unsigned short)b;
  }
  __syncthreads();
  // coalesced flush: consecutive li in one bucket -> consecutive global addrs
  for (int li = t; li < cntE; li += 256) {
    int b = sortedB[li];
    packed[(size_t)lbase[b] + (li - loff[b])] = sortedV[li];
  }
}

// ---- stage 4: per-bucket rowptr + in-bucket scatter (writes confined to ~8 KB) ----
__global__ __launch_bounds__(256) void buildCSR_kernel(const unsigned* __restrict__ packed,
                                                       const int* __restrict__ bstart,
                                                       int* __restrict__ rowptr,
                                                       int* __restrict__ csr, int N, int NB) {
  __shared__ int cnt[128], ex[128], fill[128];
  const int b = blockIdx.x;
  const int t = threadIdx.x;
  const int beg = bstart[b], end = bstart[b + 1];
  const int node0 = b << 7;
  const int nn = min(128, N - node0);
  if (t < 128) { cnt[t] = 0; fill[t] = 0; }
  __syncthreads();
  for (int i = beg + t; i < end; i += 256) {
    int j = (packed[i] >> 20) & 127;
    atomicAdd(&cnt[j], 1);
  }
  __syncthreads();
  if (t < 128) ex[t] = cnt[t];
  __syncthreads();
  for (int off = 1; off < 128; off <<= 1) {
    int u = (t >= off && t < 128) ? ex[t - off] : 0;
    __syncthreads();
    if (t < 128) ex[t] += u;
    __syncthreads();
  }
  if (t < 128) ex[t] -= cnt[t];  // exclusive
  __syncthreads();
  if (t < nn) rowptr[node0 + t] = beg + ex[t];
  if (b == NB - 1 && t == 0) rowptr[N] = end;
  for (int i = beg + t; i < end; i += 256) {
    unsigned v = packed[i];
    int j = (v >> 20) & 127;
    int r = atomicAdd(&fill[j], 1);
    csr[beg + ex[j] + r] = (int)(v & 0xFFFFFu);
  }
}

// ---------------- GEMM1 (MFMA bf16): h1 = bf16(x) @ bf16(W1) [N,128]x[128,128] ----------------
__global__ __launch_bounds__(256) void gemm1_mfma(
    const float* __restrict__ x, const unsigned short* __restrict__ w1t,
    unsigned short* __restrict__ h1u, int N) {
  __shared__ unsigned short sx[64 * 136];
  __shared__ unsigned short sw[128 * 136];
  const int t = threadIdx.x;
  const int row0 = blockIdx.x * 64;
  for (int i = t; i < 4096; i += 256) {
    int c = i >> 5, k4 = (i & 31) * 4;
    *(ushort4*)&sw[c * 136 + k4] = *(const ushort4*)&w1t[c * 128 + k4];
  }
  for (int i = t; i < 2048; i += 256) {
    int r = i >> 5, c4 = (i & 31) * 4;
    float4 v = make_float4(0.f, 0.f, 0.f, 0.f);
    if (row0 + r < N) v = *(const float4*)(x + (size_t)(row0 + r) * 128 + c4);
    ushort4 b; b.x = bf16_1(v.x); b.y = bf16_1(v.y); b.z = bf16_1(v.z); b.w = bf16_1(v.w);
    *(ushort4*)&sx[r * 136 + c4] = b;
  }
  __syncthreads();
  const int lane = t & 63, wave = t >> 6;
  const int m = lane & 15, quad = lane >> 4;
  const unsigned short* arow = &sx[(wave * 16 + m) * 136];
  short8 A[4];
#pragma unroll
  for (int ks = 0; ks < 4; ++ks) A[ks] = *(const short8*)&arow[ks * 32 + quad * 8];
  const int g = row0 + wave * 16 + quad * 4;
#pragma unroll
  for (int nt = 0; nt < 8; ++nt) {
    const unsigned short* brow = &sw[(nt * 16 + m) * 136];
    f32x4 acc = {0.f, 0.f, 0.f, 0.f};
#pragma unroll
    for (int ks = 0; ks < 4; ++ks) {
      short8 B = *(const short8*)&brow[ks * 32 + quad * 8];
      acc = __builtin_amdgcn_mfma_f32_16x16x32_bf16(A[ks], B, acc, 0, 0, 0);
    }
    int col = nt * 16 + m;
#pragma unroll
    for (int r = 0; r < 4; ++r) {
      int gr = g + r;
      if (gr < N) h1u[(size_t)gr * 128 + col] = bf16_1(acc[r]);
    }
  }
}

// ---------------- GEMM2 (MFMA bf16): h2 = houtb @ bf16(W2) [N,128]x[128,32] ----------------
__global__ __launch_bounds__(256) void gemm2_mfma(
    const unsigned* __restrict__ houtb, const unsigned short* __restrict__ w2t,
    unsigned short* __restrict__ h2u, int N) {
  __shared__ unsigned short sx[64 * 136];
  __shared__ unsigned short sw[32 * 136];
  const int t = threadIdx.x;
  const int row0 = blockIdx.x * 64;
  for (int i = t; i < 1024; i += 256) {
    int c = i >> 5, k4 = (i & 31) * 4;
    *(ushort4*)&sw[c * 136 + k4] = *(const ushort4*)&w2t[c * 128 + k4];
  }
  for (int i = t; i < 2048; i += 256) {
    int r = i >> 5, d2 = (i & 31) * 2;
    uint2 v = make_uint2(0u, 0u);
    if (row0 + r < N) v = *(const uint2*)(houtb + (size_t)(row0 + r) * 64 + d2);
    *(uint2*)&sx[r * 136 + d2 * 2] = v;
  }
  __syncthreads();
  const int lane = t & 63, wave = t >> 6;
  const int m = lane & 15, quad = lane >> 4;
  const unsigned short* arow = &sx[(wave * 16 + m) * 136];
  short8 A[4];
#pragma unroll
  for (int ks = 0; ks < 4; ++ks) A[ks] = *(const short8*)&arow[ks * 32 + quad * 8];
  const int g = row0 + wave * 16 + quad * 4;
#pragma unroll
  for (int nt = 0; nt < 2; ++nt) {
    const unsigned short* brow = &sw[(nt * 16 + m) * 136];
    f32x4 acc = {0.f, 0.f, 0.f, 0.f};
#pragma unroll
    for (int ks = 0; ks < 4; ++ks) {
      short8 B = *(const short8*)&brow[ks * 32 + quad * 8];
      acc = __builtin_amdgcn_mfma_f32_16x16x32_bf16(A[ks], B, acc, 0, 0, 0);
    }
    int col = nt * 16 + m;
#pragma unroll
    for (int r = 0; r < 4; ++r) {
      int gr = g + r;
      if (gr < N) h2u[(size_t)gr * 32 + col] = bf16_1(acc[r]);
    }
  }
}

// ---------------- al1: attention logits from bf16 h1 (one wave per node) ----------------
__global__ __launch_bounds__(256) void al1_kernel(
    const unsigned* __restrict__ h1b, const float* __restrict__ a1s, const float* __restrict__ a1d,
    float* __restrict__ al_s, float* __restrict__ al_d, int N) {
  int t = threadIdx.x;
  int n = (blockIdx.x * 256 + t) >> 6;
  if (n >= N) return;
  int lane = t & 63;
  unsigned u = h1b[(size_t)n * 64 + lane];
  float lo = bf_lo(u), hi = bf_hi(u);
  int c = 2 * lane;
  float ps = lo * a1s[c] + hi * a1s[c + 1];
  float pd = lo * a1d[c] + hi * a1d[c + 1];
#pragma unroll
  for (int off = 1; off < 16; off <<= 1) { ps += __shfl_xor(ps, off); pd += __shfl_xor(pd, off); }
  if ((lane & 15) == 0) {
    al_s[(size_t)n * 4 + (lane >> 4)] = ps;
    al_d[(size_t)n * 4 + (lane >> 4)] = pd;
  }
}

// ---------------- al2: 16 lanes per node ----------------
__global__ __launch_bounds__(256) void al2_kernel(
    const unsigned* __restrict__ h2b, const float* __restrict__ a2s, const float* __restrict__ a2d,
    float* __restrict__ al_s, float* __restrict__ al_d, int N) {
  int t = threadIdx.x;
  int n = (blockIdx.x * 256 + t) >> 4;
  if (n >= N) return;
  int l = t & 15;
  unsigned u = h2b[(size_t)n * 16 + l];
  float lo = bf_lo(u), hi = bf_hi(u);
  int c = 2 * l;
  float ps = lo * a2s[c] + hi * a2s[c + 1];
  float pd = lo * a2d[c] + hi * a2d[c + 1];
#pragma unroll
  for (int off = 1; off < 16; off <<= 1) { ps += __shfl_xor(ps, off); pd += __shfl_xor(pd, off); }
  if (l == 0) { al_s[n] = ps; al_d[n] = pd; }
}

// ---------------- Layer-1 aggregate: one wave per dst node, 8-edge groups ----------------
__global__ __launch_bounds__(256) void agg1_kernel(
    const int* __restrict__ rowptr, const int* __restrict__ csr_src,
    const unsigned* __restrict__ h1b, const float* __restrict__ al_s, const float* __restrict__ al_d,
    const float* __restrict__ b1, unsigned* __restrict__ houtb, int N) {
  int t = threadIdx.x;
  int d = (blockIdx.x * 256 + t) >> 6;
  if (d >= N) return;
  int lane = t & 63;
  int head = lane >> 4;   // head for my feature pair (cols 2*lane, 2*lane+1)
  int he = lane & 3;      // head for my exp-phase combo
  float ald_h = al_d[(size_t)d * 4 + head];
  float ald_e = al_d[(size_t)d * 4 + he];
  float accx, accy, den;
  {  // self loop
    float e = al_s[(size_t)d * 4 + head] + ald_h;
    e = fmaxf(e, 0.2f * e);
    float ex = __expf(e);
    unsigned u = h1b[(size_t)d * 64 + lane];
    accx = ex * bf_lo(u); accy = ex * bf_hi(u); den = ex;
  }
  int beg = rowptr[d], end = rowptr[d + 1];
  for (int i = beg; i < end; i += 8) {
    int idx = i + ((lane >> 2) & 7);
    int sj = (idx < end) ? csr_src[idx] : d;
    float e = al_s[(size_t)sj * 4 + he] + ald_e;
    e = fmaxf(e, 0.2f * e);
    float ex = __expf(e);
    if (idx >= end) ex = 0.f;
#pragma unroll
    for (int j = 0; j < 8; ++j) {
      int s = __shfl(sj, j * 4);
      float exj = __shfl(ex, j * 4 + head);
      unsigned u = h1b[(size_t)s * 64 + lane];
      accx += exj * bf_lo(u);
      accy += exj * bf_hi(u);
      den += exj;
    }
  }
  float inv = 1.f / den;
  float ox = accx * inv + b1[2 * lane];
  float oy = accy * inv + b1[2 * lane + 1];
  ox = ox > 0.f ? ox : expm1f(ox);  // ELU
  oy = oy > 0.f ? oy : expm1f(oy);
  houtb[(size_t)d * 64 + lane] = bfpack(ox, oy);
}

// ---------------- Layer-2 aggregate + pooled partials: half-wave per node, 8-edge groups ----------------
__global__ __launch_bounds__(256) void agg2_kernel(
    const int* __restrict__ rowptr, const int* __restrict__ csr_src,
    const unsigned* __restrict__ h2b, const float* __restrict__ al_s, const float* __restrict__ al_d,
    float* __restrict__ partial, int N) {
  __shared__ float sp[8 * 32];
  int t = threadIdx.x;
  int lane = t & 63;
  int slot = t >> 5;
  int c = t & 31;
  int node = blockIdx.x * 8 + slot;
  float o = 0.f;
  if (node < N) {
    int cw = c >> 1;
    int sh_amt = (c & 1) ? 0 : 16;
    float ald = al_d[node];
    float acc = 0.f, den = 0.f;
    {  // self loop
      float e = al_s[node] + ald;
      e = fmaxf(e, 0.2f * e);
      float ex = __expf(e);
      unsigned u = h2b[(size_t)node * 16 + cw];
      acc += ex * __uint_as_float((u << sh_amt) & 0xFFFF0000u);
      den += ex;
    }
    int beg = rowptr[node], end = rowptr[node + 1];
    for (int i = beg; i < end; i += 8) {
      int idx = i + (lane & 7);
      int sj = (idx < end) ? csr_src[idx] : node;
      float e = al_s[sj] + ald;
      e = fmaxf(e, 0.2f * e);
      float ex = __expf(e);
      if (idx >= end) ex = 0.f;
#pragma unroll
      for (int j = 0; j < 8; ++j) {
        int lsrc = (lane & 32) | j;
        int s = __shfl(sj, lsrc);
        float exj = __shfl(ex, lsrc);
        unsigned u = h2b[(size_t)s * 16 + cw];
        acc += exj * __uint_as_float((u << sh_amt) & 0xFFFF0000u);
        den += exj;
      }
    }
    o = acc / den;
  }
  sp[slot * 32 + c] = o;
  __syncthreads();
  if (t < 32) {
    float s = 0.f;
#pragma unroll
    for (int j = 0; j < 8; ++j) s += sp[j * 32 + t];
    partial[(size_t)blockIdx.x * 32 + t] = s;
  }
}

// ---------------- reduce stage: partial[nb][32] -> partial2[128][32] ----------------
__global__ __launch_bounds__(256) void reduce_kernel(
    const float* __restrict__ partial, int nb, float* __restrict__ partial2) {
  __shared__ float sp[8 * 32];
  int t = threadIdx.x;
  int slot = t >> 5, c = t & 31;
  int row0 = blockIdx.x * 8 + slot;
  float s = 0.f;
  for (int i = row0; i < nb; i += 1024) s += partial[(size_t)i * 32 + c];
  sp[slot * 32 + c] = s;
  __syncthreads();
  if (t < 32) {
    float tot = 0.f;
#pragma unroll
    for (int j = 0; j < 8; ++j) tot += sp[j * 32 + t];
    partial2[(size_t)blockIdx.x * 32 + t] = tot;
  }
}

// ---------------- final: pool mean + linear + softmax ----------------
__global__ void final_kernel(const float* __restrict__ partial2, int nb,
                             const float* __restrict__ b2, const float* __restrict__ linW,
                             const float* __restrict__ linb, float* __restrict__ out, int N) {
  __shared__ float sd[256];
  __shared__ float pooled[32];
  int t = threadIdx.x;
  int c = t & 31, g = t >> 5;
  float s = 0.f;
  for (int i = g; i < nb; i += 8) s += partial2[(size_t)i * 32 + c];
  sd[t] = s; __syncthreads();
  if (t < 32) {
    float tot = 0.f;
#pragma unroll
    for (int j = 0; j < 8; ++j) tot += sd[j * 32 + t];
    pooled[t] = tot / (float)N + b2[t];
  }
  __syncthreads();
  if (t == 0) {
    float lg[3];
    for (int j = 0; j < 3; ++j) lg[j] = linb[j];
    for (int cc = 0; cc < 32; ++cc)
      for (int j = 0; j < 3; ++j) lg[j] += pooled[cc] * linW[cc * 3 + j];
    float m = fmaxf(lg[0], fmaxf(lg[1], lg[2]));
    float e0 = __expf(lg[0] - m), e1 = __expf(lg[1] - m), e2 = __expf(lg[2] - m);
    float inv = 1.f / (e0 + e1 + e2);
    out[0] = e0 * inv; out[1] = e1 * inv; out[2] = e2 * inv;
  }
}

extern "C" void kernel_launch(void* const* d_in, const int* in_sizes, int n_in,
                              void* d_out, int out_size, void* d_ws, size_t ws_size,
                              hipStream_t stream) {
  const float* x    = (const float*)d_in[0];
  const void*  eidx = d_in[1];
  const float* W1   = (const float*)d_in[2];
  const float* a1s  = (const float*)d_in[3];
  const float* a1d  = (const float*)d_in[4];
  const float* b1   = (const float*)d_in[5];
  const float* W2   = (const float*)d_in[6];
  const float* a2s  = (const float*)d_in[7];
  const float* a2d  = (const float*)d_in[8];
  const float* b2   = (const float*)d_in[9];
  const float* linW = (const float*)d_in[10];
  const float* linb = (const float*)d_in[11];
  float* out = (float*)d_out;

  const int N = in_sizes[0] / 128;
  const int E = in_sizes[1] / 2;
  const int NB = (N + 127) >> 7;   // 128-node buckets; must be <= 1024

  char* ws = (char*)d_ws;
  size_t off = 0;
  auto alloc = [&](size_t bytes) -> void* {
    size_t o = off;
    off = align_up(off + bytes, 256);
    return (void*)(ws + o);
  };
  int* bcnt   = (int*)alloc((size_t)2 * 1024 * sizeof(int));  // bcnt + fillB, one memset
  int* fillB  = bcnt + 1024;
  int* flag   = (int*)alloc(sizeof(int));
  int* bstart = (int*)alloc((size_t)(NB + 1) * sizeof(int));
  int* rowptr = (int*)alloc((size_t)(N + 1) * sizeof(int));
  unsigned* packed = (unsigned*)alloc((size_t)E * sizeof(unsigned));
  int* csr    = (int*)alloc((size_t)E * sizeof(int));
  float* al1s = (float*)alloc((size_t)N * 4 * sizeof(float));
  float* al1d = (float*)alloc((size_t)N * 4 * sizeof(float));
  float* al2s = (float*)alloc((size_t)N * sizeof(float));
  float* al2d = (float*)alloc((size_t)N * sizeof(float));
  unsigned short* w1t = (unsigned short*)alloc(16384 * sizeof(unsigned short));
  unsigned short* w2t = (unsigned short*)alloc(4096 * sizeof(unsigned short));
  unsigned* h1b   = (unsigned*)alloc((size_t)N * 64 * sizeof(unsigned));  // bf16 [N][128]
  unsigned* houtb = (unsigned*)alloc((size_t)N * 64 * sizeof(unsigned));  // bf16 ELU'd layer-1 out
  unsigned* h2b   = (unsigned*)alloc((size_t)N * 16 * sizeof(unsigned));  // bf16 [N][32]
  const int nAggBlocks = (N + 7) / 8;
  float* partial  = (float*)alloc((size_t)nAggBlocks * 32 * sizeof(float));
  float* partial2 = (float*)alloc((size_t)128 * 32 * sizeof(float));

  hipMemsetAsync(bcnt, 0, (size_t)2 * 1024 * sizeof(int), stream);
  int ncheck = E < 512 ? E : 512;
  detect_kernel<<<1, 256, 0, stream>>>((const unsigned int*)eidx, ncheck, flag);
  prep_kernel<<<80, 256, 0, stream>>>(W1, W2, w1t, w2t);

  bhist_kernel<<<256, 256, 0, stream>>>(eidx, flag, E, bcnt, NB);
  scanB_kernel<<<1, 256, 0, stream>>>(bcnt, bstart, NB);
  sortA_kernel<<<(E + 2047) / 2048, 256, 0, stream>>>(eidx, flag, E, bstart, fillB, packed, NB);
  buildCSR_kernel<<<NB, 256, 0, stream>>>(packed, bstart, rowptr, csr, N, NB);

  const int gemmBlocks = (N + 63) / 64;
  gemm1_mfma<<<gemmBlocks, 256, 0, stream>>>(x, w1t, (unsigned short*)h1b, N);
  al1_kernel<<<(N * 64 + 255) / 256, 256, 0, stream>>>(h1b, a1s, a1d, al1s, al1d, N);
  agg1_kernel<<<(N * 64 + 255) / 256, 256, 0, stream>>>(rowptr, csr, h1b, al1s, al1d, b1, houtb, N);
  gemm2_mfma<<<gemmBlocks, 256, 0, stream>>>(houtb, w2t, (unsigned short*)h2b, N);
  al2_kernel<<<(N * 16 + 255) / 256, 256, 0, stream>>>(h2b, a2s, a2d, al2s, al2d, N);
  agg2_kernel<<<nAggBlocks, 256, 0, stream>>>(rowptr, csr, h2b, al2s, al2d, partial, N);
  reduce_kernel<<<128, 256, 0, stream>>>(partial, nAggBlocks, partial2);
  final_kernel<<<1, 256, 0, stream>>>(partial2, 128, b2, linW, linb, out, N);
}